// Round 1
// baseline (350.123 us; speedup 1.0000x reference)
//
#include <hip/hip_runtime.h>
#include <hip/hip_bf16.h>

#define N_SEQ 2048
#define NB 8
#define DM 512
#define KD 64
#define NF 70

// ---------------------------------------------------------------------------
// Kernel 1: f_theta  -> Bmat[N,N]
// cos(k)+sin(k) = sqrt(2)*sin(k+pi/4); 2 elements per thread to amortize.
// W_r/C read with uniform index -> scalar loads (SMEM), no LDS needed.
// ---------------------------------------------------------------------------
__global__ __launch_bounds__(256) void ftheta_kernel(
    const float* __restrict__ bias, const float* __restrict__ Wr,
    const float* __restrict__ Cc, const float* __restrict__ logp,
    float* __restrict__ Bmat)
{
    const float PH = 0.78539816339744830962f;   // pi/4
    const float SQ2 = 1.41421356237309504880f;
    int tid = threadIdx.x;
    long i0 = (long)blockIdx.x * 512 + tid;
    long i1 = i0 + 256;
    float4 a = ((const float4*)bias)[i0];
    float4 b = ((const float4*)bias)[i1];
    float acc0 = 0.f, acc1 = 0.f;
#pragma unroll 2
    for (int f = 0; f < NF; ++f) {
        float w0 = Wr[2*f], w1 = Wr[2*f+1], cf = Cc[f];
        // element 0
        float k1 = fmaf(a.x, w0, fmaf(a.y, w1, PH));
        float k2 = fmaf(a.z, w0, fmaf(a.w, w1, PH));
        acc0 += cf * (__sinf(k1) - __sinf(k2));
        // element 1
        float k3 = fmaf(b.x, w0, fmaf(b.y, w1, PH));
        float k4 = fmaf(b.z, w0, fmaf(b.w, w1, PH));
        acc1 += cf * (__sinf(k3) - __sinf(k4));
    }
    float p = expf(logp[0]);
    p = fminf(fmaxf(p, 0.5f), 3.0f);
    float s0 = fabsf(acc0) * SQ2 + 1e-6f;
    float s1 = fabsf(acc1) * SQ2 + 1e-6f;
    Bmat[i0] = expf(-powf(s0, p));
    Bmat[i1] = expf(-powf(s1, p));
}

// ---------------------------------------------------------------------------
// Kernel 2: QKV projection. Block handles 32 rows of flattened [B*N].
// src tile broadcast-read from LDS; W (3x64x512) chunked through LDS.
// ---------------------------------------------------------------------------
__global__ __launch_bounds__(256) void qkv_kernel(
    const float* __restrict__ src, const float* __restrict__ Wq,
    const float* __restrict__ Wk, const float* __restrict__ Wv,
    float* __restrict__ Qo, float* __restrict__ Ko, float* __restrict__ Vo)
{
    __shared__ float sS[32][68];    // [row][d] chunk, b128-aligned stride
    __shared__ float sW[192][65];   // [mat*64+c][d] chunk
    int tid = threadIdx.x;
    long bn0 = (long)blockIdx.x * 32;
    int c = tid & 63, wg = tid >> 6;
    float aQ[8], aK[8], aV[8];
#pragma unroll
    for (int r = 0; r < 8; ++r) { aQ[r] = 0.f; aK[r] = 0.f; aV[r] = 0.f; }

    for (int ch = 0; ch < 8; ++ch) {
        int d0 = ch * 64;
        __syncthreads();
        {   // stage src: 32 rows x 16 float4 = 512 slots, 2/thread
            int s1 = tid;       int r1 = s1 >> 4, q1 = s1 & 15;
            *(float4*)&sS[r1][4*q1] =
                *(const float4*)&src[(bn0 + r1)*DM + d0 + 4*q1];
            int s2 = tid + 256; int r2 = s2 >> 4, q2 = s2 & 15;
            *(float4*)&sS[r2][4*q2] =
                *(const float4*)&src[(bn0 + r2)*DM + d0 + 4*q2];
        }
        {   // stage W: 192 rows x 16 float4 = 3072 slots, 12/thread
#pragma unroll
            for (int j = 0; j < 12; ++j) {
                int s = tid + j*256; int cw = s >> 4; int k4 = s & 15;
                const float* Wp = (cw < 64) ? Wq : (cw < 128 ? Wk : Wv);
                int cc = cw & 63;
                float4 w4 = *(const float4*)&Wp[(long)cc*DM + d0 + 4*k4];
                sW[cw][4*k4+0] = w4.x; sW[cw][4*k4+1] = w4.y;
                sW[cw][4*k4+2] = w4.z; sW[cw][4*k4+3] = w4.w;
            }
        }
        __syncthreads();
#pragma unroll 4
        for (int d = 0; d < 64; ++d) {
            float wq = sW[c][d], wk = sW[64+c][d], wv = sW[128+c][d];
#pragma unroll
            for (int r = 0; r < 8; ++r) {
                float sv = sS[wg + 4*r][d];
                aQ[r] = fmaf(sv, wq, aQ[r]);
                aK[r] = fmaf(sv, wk, aK[r]);
                aV[r] = fmaf(sv, wv, aV[r]);
            }
        }
    }
#pragma unroll
    for (int r = 0; r < 8; ++r) {
        long row = bn0 + wg + 4*r;
        Qo[row*KD + c] = aQ[r];
        Ko[row*KD + c] = aK[r];
        Vo[row*KD + c] = aV[r];
    }
}

// ---------------------------------------------------------------------------
// Kernel 3: fused attention (flash-style, fp32).
// Block: 256 thr, 32 n-rows of one batch. m-tiles of 64.
// thread: tm=tid&15 (4 m's), tn=tid>>4 (rows tn, tn+16) in both phases.
// K stored transposed+XOR-swizzled for conflict-free b128 reads & writes.
// bid = ntile*8 + b so XCD x <-> batch x (K/V L2-resident).
// ---------------------------------------------------------------------------
__global__ __launch_bounds__(256) void attn_kernel(
    const float* __restrict__ Qg, const float* __restrict__ Kg,
    const float* __restrict__ Vg, const float* __restrict__ Bmat,
    const float* __restrict__ mult, const float* __restrict__ sp,
    float* __restrict__ out)
{
    __shared__ float sQ[32][65];
    __shared__ float sKT[64][64];   // [k][ ((m>>2)^(k>>2))*4 + (m&3) ]
    __shared__ float sV[64][64];    // [m][k]
    __shared__ float sP[32][68];
    int tid = threadIdx.x;
    int b = blockIdx.x & 7, nt = blockIdx.x >> 3;
    int n0 = nt * 32;
    int tm = tid & 15, tn = tid >> 4;
    float s = sp[0];

    // stage Q (32x64)
#pragma unroll
    for (int j = 0; j < 2; ++j) {
        int sl = tid + j*256; int qn = sl >> 4; int k4 = sl & 15;
        float4 q4 = *(const float4*)&Qg[((long)b*N_SEQ + n0 + qn)*KD + 4*k4];
        sQ[qn][4*k4+0] = q4.x; sQ[qn][4*k4+1] = q4.y;
        sQ[qn][4*k4+2] = q4.z; sQ[qn][4*k4+3] = q4.w;
    }

    float M0 = -1e30f, M1 = -1e30f, L0 = 0.f, L1 = 0.f;
    float acc0[4] = {0,0,0,0}, acc1[4] = {0,0,0,0};
    int row0 = n0 + tn, row1 = row0 + 16;

    for (int mt = 0; mt < 32; ++mt) {
        int m0 = mt * 64;
        __syncthreads();   // prev PV done before overwriting K/V/P
        // stage K^T (swizzled scatter) and V (direct)
#pragma unroll
        for (int j = 0; j < 4; ++j) {
            int sl = tid + j*256; int mm = sl >> 4; int k4 = sl & 15;
            long gofs = ((long)b*N_SEQ + m0 + mm)*KD + 4*k4;
            float4 kk = *(const float4*)&Kg[gofs];
            float4 vv = *(const float4*)&Vg[gofs];
            int pg = (((mm>>2) ^ k4) << 2) + (mm & 3);
            sKT[4*k4+0][pg] = kk.x;
            sKT[4*k4+1][pg] = kk.y;
            sKT[4*k4+2][pg] = kk.z;
            sKT[4*k4+3][pg] = kk.w;
            *(float4*)&sV[mm][4*k4] = vv;
        }
        // bias/mult loads (overlap with staging)
        float4 B0 = *(const float4*)&Bmat[(long)row0*N_SEQ + m0 + 4*tm];
        float4 B1 = *(const float4*)&Bmat[(long)row1*N_SEQ + m0 + 4*tm];
        float4 U0 = *(const float4*)&mult[((long)b*N_SEQ + row0)*N_SEQ + m0 + 4*tm];
        float4 U1 = *(const float4*)&mult[((long)b*N_SEQ + row1)*N_SEQ + m0 + 4*tm];
        __syncthreads();

        // QK^T: 8 logits/thread
        float lg0[4] = {0,0,0,0}, lg1[4] = {0,0,0,0};
#pragma unroll 8
        for (int k = 0; k < 64; ++k) {
            float4 kv = *(float4*)&sKT[k][((tm ^ (k>>2)) << 2)];
            float q0 = sQ[tn][k], q1 = sQ[tn+16][k];
            lg0[0] = fmaf(q0, kv.x, lg0[0]);
            lg0[1] = fmaf(q0, kv.y, lg0[1]);
            lg0[2] = fmaf(q0, kv.z, lg0[2]);
            lg0[3] = fmaf(q0, kv.w, lg0[3]);
            lg1[0] = fmaf(q1, kv.x, lg1[0]);
            lg1[1] = fmaf(q1, kv.y, lg1[1]);
            lg1[2] = fmaf(q1, kv.z, lg1[2]);
            lg1[3] = fmaf(q1, kv.w, lg1[3]);
        }
        // logits = (qk + B)/8 * (s*mult)
        lg0[0] = (lg0[0] + B0.x) * 0.125f * (s * U0.x);
        lg0[1] = (lg0[1] + B0.y) * 0.125f * (s * U0.y);
        lg0[2] = (lg0[2] + B0.z) * 0.125f * (s * U0.z);
        lg0[3] = (lg0[3] + B0.w) * 0.125f * (s * U0.w);
        lg1[0] = (lg1[0] + B1.x) * 0.125f * (s * U1.x);
        lg1[1] = (lg1[1] + B1.y) * 0.125f * (s * U1.y);
        lg1[2] = (lg1[2] + B1.z) * 0.125f * (s * U1.z);
        lg1[3] = (lg1[3] + B1.w) * 0.125f * (s * U1.w);

        // online softmax (16-lane row groups)
        float t0 = fmaxf(fmaxf(lg0[0], lg0[1]), fmaxf(lg0[2], lg0[3]));
        float t1 = fmaxf(fmaxf(lg1[0], lg1[1]), fmaxf(lg1[2], lg1[3]));
#pragma unroll
        for (int msk = 1; msk < 16; msk <<= 1) {
            t0 = fmaxf(t0, __shfl_xor(t0, msk));
            t1 = fmaxf(t1, __shfl_xor(t1, msk));
        }
        float Mn0 = fmaxf(M0, t0), Mn1 = fmaxf(M1, t1);
        float sc0 = __expf(M0 - Mn0), sc1 = __expf(M1 - Mn1);
        lg0[0] = __expf(lg0[0] - Mn0); lg0[1] = __expf(lg0[1] - Mn0);
        lg0[2] = __expf(lg0[2] - Mn0); lg0[3] = __expf(lg0[3] - Mn0);
        lg1[0] = __expf(lg1[0] - Mn1); lg1[1] = __expf(lg1[1] - Mn1);
        lg1[2] = __expf(lg1[2] - Mn1); lg1[3] = __expf(lg1[3] - Mn1);
        float ps0 = (lg0[0] + lg0[1]) + (lg0[2] + lg0[3]);
        float ps1 = (lg1[0] + lg1[1]) + (lg1[2] + lg1[3]);
#pragma unroll
        for (int msk = 1; msk < 16; msk <<= 1) {
            ps0 += __shfl_xor(ps0, msk);
            ps1 += __shfl_xor(ps1, msk);
        }
        L0 = L0 * sc0 + ps0; M0 = Mn0;
        L1 = L1 * sc1 + ps1; M1 = Mn1;
        *(float4*)&sP[tn][4*tm]    = make_float4(lg0[0], lg0[1], lg0[2], lg0[3]);
        *(float4*)&sP[tn+16][4*tm] = make_float4(lg1[0], lg1[1], lg1[2], lg1[3]);
        __syncthreads();

        // PV: cols 4*tm..4*tm+3 (tk == tm), rows tn / tn+16
#pragma unroll
        for (int j = 0; j < 4; ++j) { acc0[j] *= sc0; acc1[j] *= sc1; }
#pragma unroll 8
        for (int m = 0; m < 64; ++m) {
            float4 vv = *(float4*)&sV[m][4*tm];
            float pa = sP[tn][m], pb = sP[tn+16][m];
            acc0[0] = fmaf(pa, vv.x, acc0[0]);
            acc0[1] = fmaf(pa, vv.y, acc0[1]);
            acc0[2] = fmaf(pa, vv.z, acc0[2]);
            acc0[3] = fmaf(pa, vv.w, acc0[3]);
            acc1[0] = fmaf(pb, vv.x, acc1[0]);
            acc1[1] = fmaf(pb, vv.y, acc1[1]);
            acc1[2] = fmaf(pb, vv.z, acc1[2]);
            acc1[3] = fmaf(pb, vv.w, acc1[3]);
        }
    }
    float r0 = 1.0f / L0, r1 = 1.0f / L1;
    float4 o0 = make_float4(acc0[0]*r0, acc0[1]*r0, acc0[2]*r0, acc0[3]*r0);
    float4 o1 = make_float4(acc1[0]*r1, acc1[1]*r1, acc1[2]*r1, acc1[3]*r1);
    *(float4*)&out[((long)b*N_SEQ + row0)*KD + 4*tm] = o0;
    *(float4*)&out[((long)b*N_SEQ + row1)*KD + 4*tm] = o1;
}

// ---------------------------------------------------------------------------
extern "C" void kernel_launch(void* const* d_in, const int* in_sizes, int n_in,
                              void* d_out, int out_size, void* d_ws, size_t ws_size,
                              hipStream_t stream) {
    const float* src  = (const float*)d_in[0];
    const float* bias = (const float*)d_in[1];
    const float* mult = (const float*)d_in[2];
    const float* Wr   = (const float*)d_in[3];
    const float* Cc   = (const float*)d_in[4];
    const float* logp = (const float*)d_in[5];
    const float* Wq   = (const float*)d_in[6];
    const float* Wk   = (const float*)d_in[7];
    const float* Wv   = (const float*)d_in[8];
    const float* sp   = (const float*)d_in[9];
    float* outp = (float*)d_out;

    float* ws   = (float*)d_ws;
    float* Bmat = ws;                                  // 2048*2048
    float* Qw   = ws + (long)N_SEQ*N_SEQ;              // 8*2048*64
    float* Kw   = Qw + (long)NB*N_SEQ*KD;
    float* Vw   = Kw + (long)NB*N_SEQ*KD;

    ftheta_kernel<<<(N_SEQ*(long)N_SEQ)/512, 256, 0, stream>>>(bias, Wr, Cc, logp, Bmat);
    qkv_kernel<<<(NB*N_SEQ)/32, 256, 0, stream>>>(src, Wq, Wk, Wv, Qw, Kw, Vw);
    attn_kernel<<<(N_SEQ/32)*NB, 256, 0, stream>>>(Qw, Kw, Vw, Bmat, mult, sp, outp);
}

// Round 2
// 220.957 us; speedup vs baseline: 1.5846x; 1.5846x over previous
//
#include <hip/hip_runtime.h>
#include <hip/hip_bf16.h>

#define N_SEQ 2048
#define NB 8
#define DM 512
#define KD 64
#define NF 70

typedef float f32x4 __attribute__((ext_vector_type(4)));
typedef short v8s  __attribute__((ext_vector_type(8)));

__device__ __forceinline__ ushort f2bf(float x) {
    uint u = __float_as_uint(x);
    return (ushort)((u + 0x7FFFu + ((u >> 16) & 1u)) >> 16);
}
__device__ __forceinline__ float bf2f(ushort h) {
    return __uint_as_float(((uint)h) << 16);
}

// ---------------------------------------------------------------------------
// Kernel 1: f_theta -> Bmat[N,N] in bf16.
// cos(k)+sin(k) = sqrt(2)*sin(k+pi/4); 2 elements/thread.
// ---------------------------------------------------------------------------
__global__ __launch_bounds__(256) void ftheta_kernel(
    const float* __restrict__ bias, const float* __restrict__ Wr,
    const float* __restrict__ Cc, const float* __restrict__ logp,
    ushort* __restrict__ Bm)
{
    const float PH = 0.78539816339744830962f;   // pi/4
    const float SQ2 = 1.41421356237309504880f;
    int tid = threadIdx.x;
    long i0 = (long)blockIdx.x * 512 + tid;
    long i1 = i0 + 256;
    float4 a = ((const float4*)bias)[i0];
    float4 b = ((const float4*)bias)[i1];
    float acc0 = 0.f, acc1 = 0.f;
#pragma unroll 2
    for (int f = 0; f < NF; ++f) {
        float w0 = Wr[2*f], w1 = Wr[2*f+1], cf = Cc[f];
        float k1 = fmaf(a.x, w0, fmaf(a.y, w1, PH));
        float k2 = fmaf(a.z, w0, fmaf(a.w, w1, PH));
        acc0 += cf * (__sinf(k1) - __sinf(k2));
        float k3 = fmaf(b.x, w0, fmaf(b.y, w1, PH));
        float k4 = fmaf(b.z, w0, fmaf(b.w, w1, PH));
        acc1 += cf * (__sinf(k3) - __sinf(k4));
    }
    float p = expf(logp[0]);
    p = fminf(fmaxf(p, 0.5f), 3.0f);
    float s0 = fabsf(acc0) * SQ2 + 1e-6f;
    float s1 = fabsf(acc1) * SQ2 + 1e-6f;
    Bm[i0] = f2bf(expf(-powf(s0, p)));
    Bm[i1] = f2bf(expf(-powf(s1, p)));
}

// ---------------------------------------------------------------------------
// Kernel 2: QKV projection. Emits hi/lo-split bf16 for Q,K and bf16 V.
// ---------------------------------------------------------------------------
__global__ __launch_bounds__(256) void qkv_kernel(
    const float* __restrict__ src, const float* __restrict__ Wq,
    const float* __restrict__ Wk, const float* __restrict__ Wv,
    ushort* __restrict__ Qh, ushort* __restrict__ Ql,
    ushort* __restrict__ Kh, ushort* __restrict__ Kl,
    ushort* __restrict__ Vh)
{
    __shared__ float sS[32][68];
    __shared__ float sW[192][65];
    int tid = threadIdx.x;
    long bn0 = (long)blockIdx.x * 32;
    int c = tid & 63, wg = tid >> 6;
    float aQ[8], aK[8], aV[8];
#pragma unroll
    for (int r = 0; r < 8; ++r) { aQ[r] = 0.f; aK[r] = 0.f; aV[r] = 0.f; }

    for (int ch = 0; ch < 8; ++ch) {
        int d0 = ch * 64;
        __syncthreads();
        {
            int s1 = tid;       int r1 = s1 >> 4, q1 = s1 & 15;
            *(float4*)&sS[r1][4*q1] =
                *(const float4*)&src[(bn0 + r1)*DM + d0 + 4*q1];
            int s2 = tid + 256; int r2 = s2 >> 4, q2 = s2 & 15;
            *(float4*)&sS[r2][4*q2] =
                *(const float4*)&src[(bn0 + r2)*DM + d0 + 4*q2];
        }
        {
#pragma unroll
            for (int j = 0; j < 12; ++j) {
                int s = tid + j*256; int cw = s >> 4; int k4 = s & 15;
                const float* Wp = (cw < 64) ? Wq : (cw < 128 ? Wk : Wv);
                int cc = cw & 63;
                float4 w4 = *(const float4*)&Wp[(long)cc*DM + d0 + 4*k4];
                sW[cw][4*k4+0] = w4.x; sW[cw][4*k4+1] = w4.y;
                sW[cw][4*k4+2] = w4.z; sW[cw][4*k4+3] = w4.w;
            }
        }
        __syncthreads();
#pragma unroll 4
        for (int d = 0; d < 64; ++d) {
            float wq = sW[c][d], wk = sW[64+c][d], wv = sW[128+c][d];
#pragma unroll
            for (int r = 0; r < 8; ++r) {
                float sv = sS[wg + 4*r][d];
                aQ[r] = fmaf(sv, wq, aQ[r]);
                aK[r] = fmaf(sv, wk, aK[r]);
                aV[r] = fmaf(sv, wv, aV[r]);
            }
        }
    }
#pragma unroll
    for (int r = 0; r < 8; ++r) {
        long row = bn0 + wg + 4*r;
        ushort qh = f2bf(aQ[r]); float qhf = bf2f(qh);
        ushort kh = f2bf(aK[r]); float khf = bf2f(kh);
        Qh[row*KD + c] = qh;
        Ql[row*KD + c] = f2bf(aQ[r] - qhf);
        Kh[row*KD + c] = kh;
        Kl[row*KD + c] = f2bf(aK[r] - khf);
        Vh[row*KD + c] = f2bf(aV[r]);
    }
}

// ---------------------------------------------------------------------------
// Kernel 3: MFMA flash attention, m-split in 2 halves.
// Block: 256 thr (4 waves), 64 n-rows (wave w owns rows w*16..w*16+15).
// Swapped QK^T: S^T = K·Q^T so lane owns q-row n = lane&15 (softmax lane-local).
// QK split-bf16 3-term (fp32-accurate); P,V single bf16.
// PV: O^T = V^T·P^T (V transposed at staging).
// bid = ((nt*2+p)<<3)|b  so batch == XCD (K/V L2-resident).
// ---------------------------------------------------------------------------
__global__ __launch_bounds__(256, 2) void attn_mfma_kernel(
    const ushort* __restrict__ Qh, const ushort* __restrict__ Ql,
    const ushort* __restrict__ Kh, const ushort* __restrict__ Kl,
    const ushort* __restrict__ Vh, const ushort* __restrict__ Bm,
    const float* __restrict__ mult, const float* __restrict__ sp,
    float* __restrict__ Opart, float* __restrict__ Mp, float* __restrict__ Lp)
{
    __shared__ ushort sQh[64][72], sQl[64][72];
    __shared__ ushort sKh[64][72], sKl[64][72];
    __shared__ ushort sVh[64][72];              // V^T: [kv][m]
    __shared__ ushort sP[4][16][72];            // per wave: [n][m]

    int tid = threadIdx.x;
    int lane = tid & 63, w = tid >> 6;
    int g = lane >> 4, ln = lane & 15;
    int bid = blockIdx.x;
    int b = bid & 7, rest = bid >> 3, p = rest & 1, nt = rest >> 1;
    int n0 = nt * 64;

    // ---- stage Q (hi/lo), whole block's 64 rows
    long qbase = ((long)b*N_SEQ + n0) * KD;
#pragma unroll
    for (int j = 0; j < 2; ++j) {
        int slot = tid + j*256;              // 512 slots = 64 rows x 8 uint4
        int row = slot >> 3, c8 = slot & 7;
        *(uint4*)&sQh[row][8*c8] = *(const uint4*)&Qh[qbase + (long)row*KD + 8*c8];
        *(uint4*)&sQl[row][8*c8] = *(const uint4*)&Ql[qbase + (long)row*KD + 8*c8];
    }

    float s  = sp[0];
    float qs = 0.125f * s;
    float M = -1e30f, L = 0.f;
    f32x4 accO[4];
#pragma unroll
    for (int i = 0; i < 4; ++i) accO[i] = {0.f, 0.f, 0.f, 0.f};

    int ng = n0 + w*16 + ln;                 // this lane's q-row
    long brow = (long)ng * N_SEQ;
    long urow = ((long)b*N_SEQ + ng) * N_SEQ;

    for (int mt = 0; mt < 16; ++mt) {
        int m0 = p*1024 + mt*64;
        long kbase = ((long)b*N_SEQ + m0) * KD;
        __syncthreads();                     // prev-iter reads of sK/sV done
        // ---- stage K hi/lo (row-wise)
#pragma unroll
        for (int j = 0; j < 2; ++j) {
            int slot = tid + j*256;
            int row = slot >> 3, c8 = slot & 7;
            *(uint4*)&sKh[row][8*c8] = *(const uint4*)&Kh[kbase + (long)row*KD + 8*c8];
            *(uint4*)&sKl[row][8*c8] = *(const uint4*)&Kl[kbase + (long)row*KD + 8*c8];
        }
        // ---- stage V^T (column-wise coalesced loads, transposed writes)
        {
            int kv = tid & 63, mg = tid >> 6;
            ushort vv[16];
#pragma unroll
            for (int i = 0; i < 16; ++i)
                vv[i] = Vh[kbase + (long)(mg*16 + i)*KD + kv];
#pragma unroll
            for (int q = 0; q < 4; ++q)
                *(ushort4*)&sVh[kv][mg*16 + 4*q] =
                    make_ushort4(vv[4*q], vv[4*q+1], vv[4*q+2], vv[4*q+3]);
        }
        // ---- bias / multiplier for this lane's 16 logits
        ushort4 Bq[4]; float4 Uq[4];
#pragma unroll
        for (int sub = 0; sub < 4; ++sub) {
            Bq[sub] = *(const ushort4*)&Bm[brow + m0 + 16*sub + 4*g];
            Uq[sub] = *(const float4*)&mult[urow + m0 + 16*sub + 4*g];
        }
        __syncthreads();

        // ---- QK^T (swapped): S[sub] = K_sub · Q_w^T, split-bf16 3-term
        f32x4 S[4];
#pragma unroll
        for (int i = 0; i < 4; ++i) S[i] = {0.f, 0.f, 0.f, 0.f};
#pragma unroll
        for (int ks = 0; ks < 2; ++ks) {
            v8s qh = *(const v8s*)&sQh[w*16 + ln][32*ks + 8*g];
            v8s ql = *(const v8s*)&sQl[w*16 + ln][32*ks + 8*g];
#pragma unroll
            for (int sub = 0; sub < 4; ++sub) {
                v8s kh = *(const v8s*)&sKh[16*sub + ln][32*ks + 8*g];
                v8s kl = *(const v8s*)&sKl[16*sub + ln][32*ks + 8*g];
                S[sub] = __builtin_amdgcn_mfma_f32_16x16x32_bf16(kh, qh, S[sub], 0, 0, 0);
                S[sub] = __builtin_amdgcn_mfma_f32_16x16x32_bf16(kl, qh, S[sub], 0, 0, 0);
                S[sub] = __builtin_amdgcn_mfma_f32_16x16x32_bf16(kh, ql, S[sub], 0, 0, 0);
            }
        }

        // ---- logits + online softmax (lane-local row n = ln)
        float lg[16]; float mx = -1e30f;
#pragma unroll
        for (int sub = 0; sub < 4; ++sub) {
            float b0 = bf2f(Bq[sub].x), b1 = bf2f(Bq[sub].y);
            float b2 = bf2f(Bq[sub].z), b3 = bf2f(Bq[sub].w);
            lg[4*sub+0] = (S[sub][0] + b0) * Uq[sub].x * qs;
            lg[4*sub+1] = (S[sub][1] + b1) * Uq[sub].y * qs;
            lg[4*sub+2] = (S[sub][2] + b2) * Uq[sub].z * qs;
            lg[4*sub+3] = (S[sub][3] + b3) * Uq[sub].w * qs;
            mx = fmaxf(mx, fmaxf(fmaxf(lg[4*sub+0], lg[4*sub+1]),
                                 fmaxf(lg[4*sub+2], lg[4*sub+3])));
        }
        mx = fmaxf(mx, __shfl_xor(mx, 16));
        mx = fmaxf(mx, __shfl_xor(mx, 32));
        float Mn = fmaxf(M, mx);
        float sc = __expf(M - Mn);
        float ps = 0.f;
#pragma unroll
        for (int i = 0; i < 16; ++i) {
            float e = __expf(lg[i] - Mn);
            lg[i] = e; ps += e;
        }
        ps += __shfl_xor(ps, 16);
        ps += __shfl_xor(ps, 32);
        L = L * sc + ps; M = Mn;

        // ---- P -> bf16 in LDS (wave-private, no barrier needed)
#pragma unroll
        for (int sub = 0; sub < 4; ++sub)
            *(ushort4*)&sP[w][ln][16*sub + 4*g] =
                make_ushort4(f2bf(lg[4*sub+0]), f2bf(lg[4*sub+1]),
                             f2bf(lg[4*sub+2]), f2bf(lg[4*sub+3]));

        // ---- rescale O, then PV: O^T += V^T · P^T
#pragma unroll
        for (int i = 0; i < 4; ++i) accO[i] *= sc;
#pragma unroll
        for (int ks = 0; ks < 2; ++ks) {
            v8s pp = *(const v8s*)&sP[w][ln][32*ks + 8*g];
#pragma unroll
            for (int sub = 0; sub < 4; ++sub) {
                v8s vh = *(const v8s*)&sVh[16*sub + ln][32*ks + 8*g];
                accO[sub] = __builtin_amdgcn_mfma_f32_16x16x32_bf16(vh, pp, accO[sub], 0, 0, 0);
            }
        }
    }

    // ---- epilogue: unnormalized partial O^T + (M, L)
    long ob = ((long)bid*64 + (w*16 + ln)) * 64;
#pragma unroll
    for (int sub = 0; sub < 4; ++sub)
        *(f32x4*)&Opart[ob + 16*sub + 4*g] = accO[sub];
    if (g == 0) {
        Mp[bid*64 + w*16 + ln] = M;
        Lp[bid*64 + w*16 + ln] = L;
    }
}

// ---------------------------------------------------------------------------
// Kernel 4: merge the two m-halves (flash combine) + normalize.
// ---------------------------------------------------------------------------
__global__ __launch_bounds__(256) void combine_kernel(
    const float* __restrict__ Opart, const float* __restrict__ Mp,
    const float* __restrict__ Lp, float* __restrict__ out)
{
    int idx = blockIdx.x * 256 + threadIdx.x;   // 262144 float4-quads
    int kq = idx & 15;
    int row = idx >> 4;                          // b*2048 + n
    int b = row >> 11, n = row & 2047;
    int nt = n >> 6, r = n & 63;
    int bid0 = ((nt*2 + 0) << 3) | b;
    int bid1 = bid0 + 8;
    float M0 = Mp[bid0*64 + r], L0 = Lp[bid0*64 + r];
    float M1 = Mp[bid1*64 + r], L1 = Lp[bid1*64 + r];
    float Mx = fmaxf(M0, M1);
    float e0 = __expf(M0 - Mx), e1 = __expf(M1 - Mx);
    float4 O0 = *(const float4*)&Opart[((long)bid0*64 + r)*64 + 4*kq];
    float4 O1 = *(const float4*)&Opart[((long)bid1*64 + r)*64 + 4*kq];
    float inv = 1.0f / (L0*e0 + L1*e1);
    float4 o;
    o.x = (O0.x*e0 + O1.x*e1) * inv;
    o.y = (O0.y*e0 + O1.y*e1) * inv;
    o.z = (O0.z*e0 + O1.z*e1) * inv;
    o.w = (O0.w*e0 + O1.w*e1) * inv;
    *(float4*)&out[(long)row*64 + 4*kq] = o;
}

// ---------------------------------------------------------------------------
extern "C" void kernel_launch(void* const* d_in, const int* in_sizes, int n_in,
                              void* d_out, int out_size, void* d_ws, size_t ws_size,
                              hipStream_t stream) {
    const float* src  = (const float*)d_in[0];
    const float* bias = (const float*)d_in[1];
    const float* mult = (const float*)d_in[2];
    const float* Wr   = (const float*)d_in[3];
    const float* Cc   = (const float*)d_in[4];
    const float* logp = (const float*)d_in[5];
    const float* Wq   = (const float*)d_in[6];
    const float* Wk   = (const float*)d_in[7];
    const float* Wv   = (const float*)d_in[8];
    const float* sp   = (const float*)d_in[9];
    float* outp = (float*)d_out;

    const size_t QKV_E = (size_t)NB * N_SEQ * KD;       // 1048576
    ushort* wsu = (ushort*)d_ws;
    ushort* Bm = wsu;                                   // 2048*2048 shorts
    ushort* Qh = wsu + (size_t)N_SEQ * N_SEQ;
    ushort* Ql = Qh + QKV_E;
    ushort* Kh = Ql + QKV_E;
    ushort* Kl = Kh + QKV_E;
    ushort* Vh = Kl + QKV_E;
    float* Of  = (float*)(Vh + QKV_E);                  // 512*64*64 floats
    float* Mp  = Of + (size_t)512 * 64 * 64;
    float* Lp  = Mp + (size_t)512 * 64;

    ftheta_kernel<<<(N_SEQ*(long)N_SEQ)/512, 256, 0, stream>>>(bias, Wr, Cc, logp, Bm);
    qkv_kernel<<<(NB*N_SEQ)/32, 256, 0, stream>>>(src, Wq, Wk, Wv, Qh, Ql, Kh, Kl, Vh);
    attn_mfma_kernel<<<512, 256, 0, stream>>>(Qh, Ql, Kh, Kl, Vh, Bm, mult, sp, Of, Mp, Lp);
    combine_kernel<<<1024, 256, 0, stream>>>(Of, Mp, Lp, outp);
}

// Round 3
// 201.753 us; speedup vs baseline: 1.7354x; 1.0952x over previous
//
#include <hip/hip_runtime.h>
#include <hip/hip_bf16.h>

#define N_SEQ 2048
#define NB 8
#define DM 512
#define KD 64
#define NF 70

typedef float f32x4 __attribute__((ext_vector_type(4)));
typedef float f32x2 __attribute__((ext_vector_type(2)));
typedef short v8s  __attribute__((ext_vector_type(8)));

__device__ __forceinline__ ushort f2bf(float x) {
    uint u = __float_as_uint(x);
    return (ushort)((u + 0x7FFFu + ((u >> 16) & 1u)) >> 16);
}
__device__ __forceinline__ float bf2f(ushort h) {
    return __uint_as_float(((uint)h) << 16);
}

// ---------------------------------------------------------------------------
// Kernel 1: f_theta -> Bmat[N,N] in bf16.
// cos(k)+sin(k) = sqrt(2)*sin(k+pi/4). Angles computed in REVOLUTIONS with
// pre-scaled W_r (WrRev = Wr/2pi), sin via raw v_sin_f32. Both of the
// thread's elements packed in float2 -> v_pk_fma_f32 (full-rate packed fp32).
// ---------------------------------------------------------------------------
__global__ __launch_bounds__(256) void ftheta_kernel(
    const float* __restrict__ bias, const float* __restrict__ WrRev,
    const float* __restrict__ Cc, const float* __restrict__ logp,
    ushort* __restrict__ Bm)
{
    const float SQ2 = 1.41421356237309504880f;
    int tid = threadIdx.x;
    long i0 = (long)blockIdx.x * 512 + tid;
    long i1 = i0 + 256;
    float4 a = ((const float4*)bias)[i0];
    float4 b = ((const float4*)bias)[i1];
    f32x2 ux = {a.x, b.x}, vy = {a.y, b.y};   // k1 inputs, elem0/elem1 packed
    f32x2 xz = {a.z, b.z}, yw = {a.w, b.w};   // k2 inputs
    f32x2 acc = {0.f, 0.f};
    const f32x2 EI = {0.125f, 0.125f};        // pi/4 in revolutions
#pragma unroll 2
    for (int f = 0; f < NF; ++f) {
        float w0 = WrRev[2*f], w1 = WrRev[2*f+1], cf = Cc[f];
        f32x2 k1 = ux*w0 + (vy*w1 + EI);      // 2x v_pk_fma_f32
        f32x2 k2 = xz*w0 + (yw*w1 + EI);      // 2x v_pk_fma_f32
        f32x2 s1, s2;
        s1.x = __builtin_amdgcn_sinf(k1.x);   // v_sin_f32: sin(2*pi*x)
        s1.y = __builtin_amdgcn_sinf(k1.y);
        s2.x = __builtin_amdgcn_sinf(k2.x);
        s2.y = __builtin_amdgcn_sinf(k2.y);
        acc += cf * (s1 - s2);                // pk_add + pk_fma
    }
    float p = __expf(logp[0]);
    p = fminf(fmaxf(p, 0.5f), 3.0f);
    float s0 = fabsf(acc.x) * SQ2 + 1e-6f;
    float s1v = fabsf(acc.y) * SQ2 + 1e-6f;
    Bm[i0] = f2bf(__expf(-__powf(s0, p)));
    Bm[i1] = f2bf(__expf(-__powf(s1v, p)));
}

// ---------------------------------------------------------------------------
// Kernel 2: QKV projection. Emits hi/lo-split bf16 for Q,K and bf16 V.
// Block 0 additionally writes WrRev = Wr * (1/2pi)  (qkv launches before
// ftheta on the same stream, so WrRev is ready when ftheta starts).
// ---------------------------------------------------------------------------
__global__ __launch_bounds__(256) void qkv_kernel(
    const float* __restrict__ src, const float* __restrict__ Wq,
    const float* __restrict__ Wk, const float* __restrict__ Wv,
    const float* __restrict__ Wr, float* __restrict__ WrRev,
    ushort* __restrict__ Qh, ushort* __restrict__ Ql,
    ushort* __restrict__ Kh, ushort* __restrict__ Kl,
    ushort* __restrict__ Vh)
{
    __shared__ float sS[32][68];
    __shared__ float sW[192][65];
    int tid = threadIdx.x;
    if (blockIdx.x == 0 && tid < 2*NF)
        WrRev[tid] = Wr[tid] * 0.15915494309189533577f;
    long bn0 = (long)blockIdx.x * 32;
    int c = tid & 63, wg = tid >> 6;
    float aQ[8], aK[8], aV[8];
#pragma unroll
    for (int r = 0; r < 8; ++r) { aQ[r] = 0.f; aK[r] = 0.f; aV[r] = 0.f; }

    for (int ch = 0; ch < 8; ++ch) {
        int d0 = ch * 64;
        __syncthreads();
        {
            int s1 = tid;       int r1 = s1 >> 4, q1 = s1 & 15;
            *(float4*)&sS[r1][4*q1] =
                *(const float4*)&src[(bn0 + r1)*DM + d0 + 4*q1];
            int s2 = tid + 256; int r2 = s2 >> 4, q2 = s2 & 15;
            *(float4*)&sS[r2][4*q2] =
                *(const float4*)&src[(bn0 + r2)*DM + d0 + 4*q2];
        }
        {
#pragma unroll
            for (int j = 0; j < 12; ++j) {
                int s = tid + j*256; int cw = s >> 4; int k4 = s & 15;
                const float* Wp = (cw < 64) ? Wq : (cw < 128 ? Wk : Wv);
                int cc = cw & 63;
                float4 w4 = *(const float4*)&Wp[(long)cc*DM + d0 + 4*k4];
                sW[cw][4*k4+0] = w4.x; sW[cw][4*k4+1] = w4.y;
                sW[cw][4*k4+2] = w4.z; sW[cw][4*k4+3] = w4.w;
            }
        }
        __syncthreads();
#pragma unroll 4
        for (int d = 0; d < 64; ++d) {
            float wq = sW[c][d], wk = sW[64+c][d], wv = sW[128+c][d];
#pragma unroll
            for (int r = 0; r < 8; ++r) {
                float sv = sS[wg + 4*r][d];
                aQ[r] = fmaf(sv, wq, aQ[r]);
                aK[r] = fmaf(sv, wk, aK[r]);
                aV[r] = fmaf(sv, wv, aV[r]);
            }
        }
    }
#pragma unroll
    for (int r = 0; r < 8; ++r) {
        long row = bn0 + wg + 4*r;
        ushort qh = f2bf(aQ[r]); float qhf = bf2f(qh);
        ushort kh = f2bf(aK[r]); float khf = bf2f(kh);
        Qh[row*KD + c] = qh;
        Ql[row*KD + c] = f2bf(aQ[r] - qhf);
        Kh[row*KD + c] = kh;
        Kl[row*KD + c] = f2bf(aK[r] - khf);
        Vh[row*KD + c] = f2bf(aV[r]);
    }
}

// ---------------------------------------------------------------------------
// Kernel 3: MFMA flash attention, m-split in 2 halves.
// Block: 256 thr (4 waves), 64 n-rows (wave w owns rows w*16..w*16+15).
// Swapped QK^T: S^T = K·Q^T so lane owns q-row n = lane&15 (softmax lane-local).
// QK split-bf16 3-term (fp32-accurate); P,V single bf16.
// PV: O^T = V^T·P^T (V transposed at staging).
// bid = ((nt*2+p)<<3)|b  so batch == XCD (K/V L2-resident).
// ---------------------------------------------------------------------------
__global__ __launch_bounds__(256, 2) void attn_mfma_kernel(
    const ushort* __restrict__ Qh, const ushort* __restrict__ Ql,
    const ushort* __restrict__ Kh, const ushort* __restrict__ Kl,
    const ushort* __restrict__ Vh, const ushort* __restrict__ Bm,
    const float* __restrict__ mult, const float* __restrict__ sp,
    float* __restrict__ Opart, float* __restrict__ Mp, float* __restrict__ Lp)
{
    __shared__ ushort sQh[64][72], sQl[64][72];
    __shared__ ushort sKh[64][72], sKl[64][72];
    __shared__ ushort sVh[64][72];              // V^T: [kv][m]
    __shared__ ushort sP[4][16][72];            // per wave: [n][m]

    int tid = threadIdx.x;
    int lane = tid & 63, w = tid >> 6;
    int g = lane >> 4, ln = lane & 15;
    int bid = blockIdx.x;
    int b = bid & 7, rest = bid >> 3, p = rest & 1, nt = rest >> 1;
    int n0 = nt * 64;

    // ---- stage Q (hi/lo), whole block's 64 rows
    long qbase = ((long)b*N_SEQ + n0) * KD;
#pragma unroll
    for (int j = 0; j < 2; ++j) {
        int slot = tid + j*256;              // 512 slots = 64 rows x 8 uint4
        int row = slot >> 3, c8 = slot & 7;
        *(uint4*)&sQh[row][8*c8] = *(const uint4*)&Qh[qbase + (long)row*KD + 8*c8];
        *(uint4*)&sQl[row][8*c8] = *(const uint4*)&Ql[qbase + (long)row*KD + 8*c8];
    }

    float s  = sp[0];
    float qs = 0.125f * s;
    float M = -1e30f, L = 0.f;
    f32x4 accO[4];
#pragma unroll
    for (int i = 0; i < 4; ++i) accO[i] = {0.f, 0.f, 0.f, 0.f};

    int ng = n0 + w*16 + ln;                 // this lane's q-row
    long brow = (long)ng * N_SEQ;
    long urow = ((long)b*N_SEQ + ng) * N_SEQ;

    for (int mt = 0; mt < 16; ++mt) {
        int m0 = p*1024 + mt*64;
        long kbase = ((long)b*N_SEQ + m0) * KD;
        __syncthreads();                     // prev-iter reads of sK/sV done
        // ---- stage K hi/lo (row-wise)
#pragma unroll
        for (int j = 0; j < 2; ++j) {
            int slot = tid + j*256;
            int row = slot >> 3, c8 = slot & 7;
            *(uint4*)&sKh[row][8*c8] = *(const uint4*)&Kh[kbase + (long)row*KD + 8*c8];
            *(uint4*)&sKl[row][8*c8] = *(const uint4*)&Kl[kbase + (long)row*KD + 8*c8];
        }
        // ---- stage V^T (column-wise coalesced loads, transposed writes)
        {
            int kv = tid & 63, mg = tid >> 6;
            ushort vv[16];
#pragma unroll
            for (int i = 0; i < 16; ++i)
                vv[i] = Vh[kbase + (long)(mg*16 + i)*KD + kv];
#pragma unroll
            for (int q = 0; q < 4; ++q)
                *(ushort4*)&sVh[kv][mg*16 + 4*q] =
                    make_ushort4(vv[4*q], vv[4*q+1], vv[4*q+2], vv[4*q+3]);
        }
        // ---- bias / multiplier for this lane's 16 logits
        ushort4 Bq[4]; float4 Uq[4];
#pragma unroll
        for (int sub = 0; sub < 4; ++sub) {
            Bq[sub] = *(const ushort4*)&Bm[brow + m0 + 16*sub + 4*g];
            Uq[sub] = *(const float4*)&mult[urow + m0 + 16*sub + 4*g];
        }
        __syncthreads();

        // ---- QK^T (swapped): S[sub] = K_sub · Q_w^T, split-bf16 3-term
        f32x4 S[4];
#pragma unroll
        for (int i = 0; i < 4; ++i) S[i] = {0.f, 0.f, 0.f, 0.f};
#pragma unroll
        for (int ks = 0; ks < 2; ++ks) {
            v8s qh = *(const v8s*)&sQh[w*16 + ln][32*ks + 8*g];
            v8s ql = *(const v8s*)&sQl[w*16 + ln][32*ks + 8*g];
#pragma unroll
            for (int sub = 0; sub < 4; ++sub) {
                v8s kh = *(const v8s*)&sKh[16*sub + ln][32*ks + 8*g];
                v8s kl = *(const v8s*)&sKl[16*sub + ln][32*ks + 8*g];
                S[sub] = __builtin_amdgcn_mfma_f32_16x16x32_bf16(kh, qh, S[sub], 0, 0, 0);
                S[sub] = __builtin_amdgcn_mfma_f32_16x16x32_bf16(kl, qh, S[sub], 0, 0, 0);
                S[sub] = __builtin_amdgcn_mfma_f32_16x16x32_bf16(kh, ql, S[sub], 0, 0, 0);
            }
        }

        // ---- logits + online softmax (lane-local row n = ln)
        float lg[16]; float mx = -1e30f;
#pragma unroll
        for (int sub = 0; sub < 4; ++sub) {
            float b0 = bf2f(Bq[sub].x), b1 = bf2f(Bq[sub].y);
            float b2 = bf2f(Bq[sub].z), b3 = bf2f(Bq[sub].w);
            lg[4*sub+0] = (S[sub][0] + b0) * Uq[sub].x * qs;
            lg[4*sub+1] = (S[sub][1] + b1) * Uq[sub].y * qs;
            lg[4*sub+2] = (S[sub][2] + b2) * Uq[sub].z * qs;
            lg[4*sub+3] = (S[sub][3] + b3) * Uq[sub].w * qs;
            mx = fmaxf(mx, fmaxf(fmaxf(lg[4*sub+0], lg[4*sub+1]),
                                 fmaxf(lg[4*sub+2], lg[4*sub+3])));
        }
        mx = fmaxf(mx, __shfl_xor(mx, 16));
        mx = fmaxf(mx, __shfl_xor(mx, 32));
        float Mn = fmaxf(M, mx);
        float sc = __expf(M - Mn);
        float ps = 0.f;
#pragma unroll
        for (int i = 0; i < 16; ++i) {
            float e = __expf(lg[i] - Mn);
            lg[i] = e; ps += e;
        }
        ps += __shfl_xor(ps, 16);
        ps += __shfl_xor(ps, 32);
        L = L * sc + ps; M = Mn;

        // ---- P -> bf16 in LDS (wave-private, no barrier needed)
#pragma unroll
        for (int sub = 0; sub < 4; ++sub)
            *(ushort4*)&sP[w][ln][16*sub + 4*g] =
                make_ushort4(f2bf(lg[4*sub+0]), f2bf(lg[4*sub+1]),
                             f2bf(lg[4*sub+2]), f2bf(lg[4*sub+3]));

        // ---- rescale O, then PV: O^T += V^T · P^T
#pragma unroll
        for (int i = 0; i < 4; ++i) accO[i] *= sc;
#pragma unroll
        for (int ks = 0; ks < 2; ++ks) {
            v8s pp = *(const v8s*)&sP[w][ln][32*ks + 8*g];
#pragma unroll
            for (int sub = 0; sub < 4; ++sub) {
                v8s vh = *(const v8s*)&sVh[16*sub + ln][32*ks + 8*g];
                accO[sub] = __builtin_amdgcn_mfma_f32_16x16x32_bf16(vh, pp, accO[sub], 0, 0, 0);
            }
        }
    }

    // ---- epilogue: unnormalized partial O^T + (M, L)
    long ob = ((long)bid*64 + (w*16 + ln)) * 64;
#pragma unroll
    for (int sub = 0; sub < 4; ++sub)
        *(f32x4*)&Opart[ob + 16*sub + 4*g] = accO[sub];
    if (g == 0) {
        Mp[bid*64 + w*16 + ln] = M;
        Lp[bid*64 + w*16 + ln] = L;
    }
}

// ---------------------------------------------------------------------------
// Kernel 4: merge the two m-halves (flash combine) + normalize.
// ---------------------------------------------------------------------------
__global__ __launch_bounds__(256) void combine_kernel(
    const float* __restrict__ Opart, const float* __restrict__ Mp,
    const float* __restrict__ Lp, float* __restrict__ out)
{
    int idx = blockIdx.x * 256 + threadIdx.x;   // 262144 float4-quads
    int kq = idx & 15;
    int row = idx >> 4;                          // b*2048 + n
    int b = row >> 11, n = row & 2047;
    int nt = n >> 6, r = n & 63;
    int bid0 = ((nt*2 + 0) << 3) | b;
    int bid1 = bid0 + 8;
    float M0 = Mp[bid0*64 + r], L0 = Lp[bid0*64 + r];
    float M1 = Mp[bid1*64 + r], L1 = Lp[bid1*64 + r];
    float Mx = fmaxf(M0, M1);
    float e0 = __expf(M0 - Mx), e1 = __expf(M1 - Mx);
    float4 O0 = *(const float4*)&Opart[((long)bid0*64 + r)*64 + 4*kq];
    float4 O1 = *(const float4*)&Opart[((long)bid1*64 + r)*64 + 4*kq];
    float inv = 1.0f / (L0*e0 + L1*e1);
    float4 o;
    o.x = (O0.x*e0 + O1.x*e1) * inv;
    o.y = (O0.y*e0 + O1.y*e1) * inv;
    o.z = (O0.z*e0 + O1.z*e1) * inv;
    o.w = (O0.w*e0 + O1.w*e1) * inv;
    *(float4*)&out[(long)row*64 + 4*kq] = o;
}

// ---------------------------------------------------------------------------
extern "C" void kernel_launch(void* const* d_in, const int* in_sizes, int n_in,
                              void* d_out, int out_size, void* d_ws, size_t ws_size,
                              hipStream_t stream) {
    const float* src  = (const float*)d_in[0];
    const float* bias = (const float*)d_in[1];
    const float* mult = (const float*)d_in[2];
    const float* Wr   = (const float*)d_in[3];
    const float* Cc   = (const float*)d_in[4];
    const float* logp = (const float*)d_in[5];
    const float* Wq   = (const float*)d_in[6];
    const float* Wk   = (const float*)d_in[7];
    const float* Wv   = (const float*)d_in[8];
    const float* sp   = (const float*)d_in[9];
    float* outp = (float*)d_out;

    const size_t QKV_E = (size_t)NB * N_SEQ * KD;       // 1048576
    ushort* wsu = (ushort*)d_ws;
    ushort* Bm = wsu;                                   // 2048*2048 shorts
    ushort* Qh = wsu + (size_t)N_SEQ * N_SEQ;
    ushort* Ql = Qh + QKV_E;
    ushort* Kh = Ql + QKV_E;
    ushort* Kl = Kh + QKV_E;
    ushort* Vh = Kl + QKV_E;
    float* Of  = (float*)(Vh + QKV_E);                  // 512*64*64 floats
    float* Mp  = Of + (size_t)512 * 64 * 64;
    float* Lp  = Mp + (size_t)512 * 64;
    float* WrRev = Lp + (size_t)512 * 64;               // 140 floats

    qkv_kernel<<<(NB*N_SEQ)/32, 256, 0, stream>>>(src, Wq, Wk, Wv, Wr, WrRev,
                                                  Qh, Ql, Kh, Kl, Vh);
    ftheta_kernel<<<(N_SEQ*(long)N_SEQ)/512, 256, 0, stream>>>(bias, WrRev, Cc, logp, Bm);
    attn_mfma_kernel<<<512, 256, 0, stream>>>(Qh, Ql, Kh, Kl, Vh, Bm, mult, sp, Of, Mp, Lp);
    combine_kernel<<<1024, 256, 0, stream>>>(Of, Mp, Lp, outp);
}

// Round 4
// 192.022 us; speedup vs baseline: 1.8233x; 1.0507x over previous
//
#include <hip/hip_runtime.h>
#include <hip/hip_bf16.h>

#define N_SEQ 2048
#define NB 8
#define DM 512
#define KD 64
#define NF 70

#define TG 512                   // table grid
#define TRANGE 6.5f              // table covers [-TRANGE, TRANGE]
#define TSCL (511.0f / 13.0f)    // (TG-1) / (2*TRANGE)
#define TOFS (6.5f * TSCL)       // 255.5

typedef float f32x4 __attribute__((ext_vector_type(4)));
typedef float f32x2 __attribute__((ext_vector_type(2)));
typedef short v8s  __attribute__((ext_vector_type(8)));

__device__ __forceinline__ ushort f2bf(float x) {
    uint u = __float_as_uint(x);
    return (ushort)((u + 0x7FFFu + ((u >> 16) & 1u)) >> 16);
}
__device__ __forceinline__ float bf2f(ushort h) {
    return __uint_as_float(((uint)h) << 16);
}

// ---------------------------------------------------------------------------
// Kernel 0: build table  g(x,y) = sum_f C_f*sqrt2*sin(x*w0+y*w1+pi/4)
// on a TGxTG grid; paired layout Tp[j*TG+i] = (g(x_i,y_j), g(x_{i+1},y_j))
// so one 8B load fetches both corners of a row.
// ---------------------------------------------------------------------------
__global__ __launch_bounds__(256) void tbuild_kernel(
    const float* __restrict__ Wr, const float* __restrict__ Cc,
    float2* __restrict__ Tp)
{
    const float SQ2 = 1.41421356237309504880f;
    const float R2PI = 0.15915494309189533577f;
    int idx = blockIdx.x * 256 + threadIdx.x;      // TG*TG threads
    int j = idx >> 9, i = idx & (TG - 1);
    const float h = 2.0f * TRANGE / (TG - 1);
    float y  = -TRANGE + j * h;
    float x0 = -TRANGE + i * h;
    float x1 = -TRANGE + min(i + 1, TG - 1) * h;
    float g0 = 0.f, g1 = 0.f;
    for (int f = 0; f < NF; ++f) {
        float w0 = Wr[2*f] * R2PI, w1 = Wr[2*f+1] * R2PI, cf = Cc[f];
        float base = fmaf(y, w1, 0.125f);
        float k0 = __builtin_amdgcn_fractf(fmaf(x0, w0, base));
        float k1 = __builtin_amdgcn_fractf(fmaf(x1, w0, base));
        g0 = fmaf(cf, __builtin_amdgcn_sinf(k0), g0);
        g1 = fmaf(cf, __builtin_amdgcn_sinf(k1), g1);
    }
    Tp[idx] = make_float2(g0 * SQ2, g1 * SQ2);
}

// ---------------------------------------------------------------------------
// Kernel 1: f_theta via 2 bilinear table lookups per element -> Bmat bf16.
// 2 elements/thread for load ILP.
// ---------------------------------------------------------------------------
__device__ __forceinline__ float tlookup(const float2* __restrict__ Tp,
                                         float x, float y)
{
    float u = fmaf(x, TSCL, TOFS);
    float v = fmaf(y, TSCL, TOFS);
    u = fminf(fmaxf(u, 0.0f), 510.999f);
    v = fminf(fmaxf(v, 0.0f), 510.999f);
    int iu = (int)u, iv = (int)v;
    float fu = __builtin_amdgcn_fractf(u);
    float fv = __builtin_amdgcn_fractf(v);
    int base = iv * TG + iu;
    float2 r0 = Tp[base];
    float2 r1 = Tp[base + TG];
    float t0 = fmaf(fu, r0.y - r0.x, r0.x);
    float t1 = fmaf(fu, r1.y - r1.x, r1.x);
    return fmaf(fv, t1 - t0, t0);
}

__global__ __launch_bounds__(256) void ftheta_kernel(
    const float* __restrict__ bias, const float2* __restrict__ Tp,
    const float* __restrict__ logp, ushort* __restrict__ Bm)
{
    int tid = threadIdx.x;
    long i0 = (long)blockIdx.x * 512 + tid;
    long i1 = i0 + 256;
    float4 a = ((const float4*)bias)[i0];
    float4 b = ((const float4*)bias)[i1];
    float gA1 = tlookup(Tp, a.x, a.y);
    float gA2 = tlookup(Tp, a.z, a.w);
    float gB1 = tlookup(Tp, b.x, b.y);
    float gB2 = tlookup(Tp, b.z, b.w);
    float s0 = fabsf(gA1 - gA2) + 1e-6f;
    float s1 = fabsf(gB1 - gB2) + 1e-6f;
    float p = __expf(logp[0]);
    p = fminf(fmaxf(p, 0.5f), 3.0f);
    if (p == 1.0f) {
        Bm[i0] = f2bf(__expf(-s0));
        Bm[i1] = f2bf(__expf(-s1));
    } else {
        Bm[i0] = f2bf(__expf(-__powf(s0, p)));
        Bm[i1] = f2bf(__expf(-__powf(s1, p)));
    }
}

// ---------------------------------------------------------------------------
// Kernel 2: QKV projection. Emits hi/lo-split bf16 for Q,K and bf16 V.
// ---------------------------------------------------------------------------
__global__ __launch_bounds__(256) void qkv_kernel(
    const float* __restrict__ src, const float* __restrict__ Wq,
    const float* __restrict__ Wk, const float* __restrict__ Wv,
    ushort* __restrict__ Qh, ushort* __restrict__ Ql,
    ushort* __restrict__ Kh, ushort* __restrict__ Kl,
    ushort* __restrict__ Vh)
{
    __shared__ float sS[32][68];
    __shared__ float sW[192][65];
    int tid = threadIdx.x;
    long bn0 = (long)blockIdx.x * 32;
    int c = tid & 63, wg = tid >> 6;
    float aQ[8], aK[8], aV[8];
#pragma unroll
    for (int r = 0; r < 8; ++r) { aQ[r] = 0.f; aK[r] = 0.f; aV[r] = 0.f; }

    for (int ch = 0; ch < 8; ++ch) {
        int d0 = ch * 64;
        __syncthreads();
        {
            int s1 = tid;       int r1 = s1 >> 4, q1 = s1 & 15;
            *(float4*)&sS[r1][4*q1] =
                *(const float4*)&src[(bn0 + r1)*DM + d0 + 4*q1];
            int s2 = tid + 256; int r2 = s2 >> 4, q2 = s2 & 15;
            *(float4*)&sS[r2][4*q2] =
                *(const float4*)&src[(bn0 + r2)*DM + d0 + 4*q2];
        }
        {
#pragma unroll
            for (int j = 0; j < 12; ++j) {
                int s = tid + j*256; int cw = s >> 4; int k4 = s & 15;
                const float* Wp = (cw < 64) ? Wq : (cw < 128 ? Wk : Wv);
                int cc = cw & 63;
                float4 w4 = *(const float4*)&Wp[(long)cc*DM + d0 + 4*k4];
                sW[cw][4*k4+0] = w4.x; sW[cw][4*k4+1] = w4.y;
                sW[cw][4*k4+2] = w4.z; sW[cw][4*k4+3] = w4.w;
            }
        }
        __syncthreads();
#pragma unroll 4
        for (int d = 0; d < 64; ++d) {
            float wq = sW[c][d], wk = sW[64+c][d], wv = sW[128+c][d];
#pragma unroll
            for (int r = 0; r < 8; ++r) {
                float sv = sS[wg + 4*r][d];
                aQ[r] = fmaf(sv, wq, aQ[r]);
                aK[r] = fmaf(sv, wk, aK[r]);
                aV[r] = fmaf(sv, wv, aV[r]);
            }
        }
    }
#pragma unroll
    for (int r = 0; r < 8; ++r) {
        long row = bn0 + wg + 4*r;
        ushort qh = f2bf(aQ[r]); float qhf = bf2f(qh);
        ushort kh = f2bf(aK[r]); float khf = bf2f(kh);
        Qh[row*KD + c] = qh;
        Ql[row*KD + c] = f2bf(aQ[r] - qhf);
        Kh[row*KD + c] = kh;
        Kl[row*KD + c] = f2bf(aK[r] - khf);
        Vh[row*KD + c] = f2bf(aV[r]);
    }
}

// ---------------------------------------------------------------------------
// Kernel 3: MFMA flash attention, m-split in 2 halves.
// Block: 256 thr (4 waves), 64 n-rows (wave w owns rows w*16..w*16+15).
// Swapped QK^T: S^T = K·Q^T so lane owns q-row n = lane&15 (softmax lane-local).
// QK split-bf16 3-term (fp32-accurate); P,V single bf16.
// PV: O^T = V^T·P^T (V transposed at staging).
// bid = ((nt*2+p)<<3)|b  so batch == XCD (K/V L2-resident).
// ---------------------------------------------------------------------------
__global__ __launch_bounds__(256, 2) void attn_mfma_kernel(
    const ushort* __restrict__ Qh, const ushort* __restrict__ Ql,
    const ushort* __restrict__ Kh, const ushort* __restrict__ Kl,
    const ushort* __restrict__ Vh, const ushort* __restrict__ Bm,
    const float* __restrict__ mult, const float* __restrict__ sp,
    float* __restrict__ Opart, float* __restrict__ Mp, float* __restrict__ Lp)
{
    __shared__ ushort sQh[64][72], sQl[64][72];
    __shared__ ushort sKh[64][72], sKl[64][72];
    __shared__ ushort sVh[64][72];              // V^T: [kv][m]
    __shared__ ushort sP[4][16][72];            // per wave: [n][m]

    int tid = threadIdx.x;
    int lane = tid & 63, w = tid >> 6;
    int g = lane >> 4, ln = lane & 15;
    int bid = blockIdx.x;
    int b = bid & 7, rest = bid >> 3, p = rest & 1, nt = rest >> 1;
    int n0 = nt * 64;

    // ---- stage Q (hi/lo), whole block's 64 rows
    long qbase = ((long)b*N_SEQ + n0) * KD;
#pragma unroll
    for (int j = 0; j < 2; ++j) {
        int slot = tid + j*256;              // 512 slots = 64 rows x 8 uint4
        int row = slot >> 3, c8 = slot & 7;
        *(uint4*)&sQh[row][8*c8] = *(const uint4*)&Qh[qbase + (long)row*KD + 8*c8];
        *(uint4*)&sQl[row][8*c8] = *(const uint4*)&Ql[qbase + (long)row*KD + 8*c8];
    }

    float s  = sp[0];
    float qs = 0.125f * s;
    float M = -1e30f, L = 0.f;
    f32x4 accO[4];
#pragma unroll
    for (int i = 0; i < 4; ++i) accO[i] = {0.f, 0.f, 0.f, 0.f};

    int ng = n0 + w*16 + ln;                 // this lane's q-row
    long brow = (long)ng * N_SEQ;
    long urow = ((long)b*N_SEQ + ng) * N_SEQ;

    for (int mt = 0; mt < 16; ++mt) {
        int m0 = p*1024 + mt*64;
        long kbase = ((long)b*N_SEQ + m0) * KD;
        __syncthreads();                     // prev-iter reads of sK/sV done
        // ---- stage K hi/lo (row-wise)
#pragma unroll
        for (int j = 0; j < 2; ++j) {
            int slot = tid + j*256;
            int row = slot >> 3, c8 = slot & 7;
            *(uint4*)&sKh[row][8*c8] = *(const uint4*)&Kh[kbase + (long)row*KD + 8*c8];
            *(uint4*)&sKl[row][8*c8] = *(const uint4*)&Kl[kbase + (long)row*KD + 8*c8];
        }
        // ---- stage V^T (column-wise coalesced loads, transposed writes)
        {
            int kv = tid & 63, mg = tid >> 6;
            ushort vv[16];
#pragma unroll
            for (int i = 0; i < 16; ++i)
                vv[i] = Vh[kbase + (long)(mg*16 + i)*KD + kv];
#pragma unroll
            for (int q = 0; q < 4; ++q)
                *(ushort4*)&sVh[kv][mg*16 + 4*q] =
                    make_ushort4(vv[4*q], vv[4*q+1], vv[4*q+2], vv[4*q+3]);
        }
        // ---- bias / multiplier for this lane's 16 logits
        ushort4 Bq[4]; float4 Uq[4];
#pragma unroll
        for (int sub = 0; sub < 4; ++sub) {
            Bq[sub] = *(const ushort4*)&Bm[brow + m0 + 16*sub + 4*g];
            Uq[sub] = *(const float4*)&mult[urow + m0 + 16*sub + 4*g];
        }
        __syncthreads();

        // ---- QK^T (swapped): S[sub] = K_sub · Q_w^T, split-bf16 3-term
        f32x4 S[4];
#pragma unroll
        for (int i = 0; i < 4; ++i) S[i] = {0.f, 0.f, 0.f, 0.f};
#pragma unroll
        for (int ks = 0; ks < 2; ++ks) {
            v8s qh = *(const v8s*)&sQh[w*16 + ln][32*ks + 8*g];
            v8s ql = *(const v8s*)&sQl[w*16 + ln][32*ks + 8*g];
#pragma unroll
            for (int sub = 0; sub < 4; ++sub) {
                v8s kh = *(const v8s*)&sKh[16*sub + ln][32*ks + 8*g];
                v8s kl = *(const v8s*)&sKl[16*sub + ln][32*ks + 8*g];
                S[sub] = __builtin_amdgcn_mfma_f32_16x16x32_bf16(kh, qh, S[sub], 0, 0, 0);
                S[sub] = __builtin_amdgcn_mfma_f32_16x16x32_bf16(kl, qh, S[sub], 0, 0, 0);
                S[sub] = __builtin_amdgcn_mfma_f32_16x16x32_bf16(kh, ql, S[sub], 0, 0, 0);
            }
        }

        // ---- logits + online softmax (lane-local row n = ln)
        float lg[16]; float mx = -1e30f;
#pragma unroll
        for (int sub = 0; sub < 4; ++sub) {
            float b0 = bf2f(Bq[sub].x), b1 = bf2f(Bq[sub].y);
            float b2 = bf2f(Bq[sub].z), b3 = bf2f(Bq[sub].w);
            lg[4*sub+0] = (S[sub][0] + b0) * Uq[sub].x * qs;
            lg[4*sub+1] = (S[sub][1] + b1) * Uq[sub].y * qs;
            lg[4*sub+2] = (S[sub][2] + b2) * Uq[sub].z * qs;
            lg[4*sub+3] = (S[sub][3] + b3) * Uq[sub].w * qs;
            mx = fmaxf(mx, fmaxf(fmaxf(lg[4*sub+0], lg[4*sub+1]),
                                 fmaxf(lg[4*sub+2], lg[4*sub+3])));
        }
        mx = fmaxf(mx, __shfl_xor(mx, 16));
        mx = fmaxf(mx, __shfl_xor(mx, 32));
        float Mn = fmaxf(M, mx);
        float sc = __expf(M - Mn);
        float ps = 0.f;
#pragma unroll
        for (int i = 0; i < 16; ++i) {
            float e = __expf(lg[i] - Mn);
            lg[i] = e; ps += e;
        }
        ps += __shfl_xor(ps, 16);
        ps += __shfl_xor(ps, 32);
        L = L * sc + ps; M = Mn;

        // ---- P -> bf16 in LDS (wave-private, no barrier needed)
#pragma unroll
        for (int sub = 0; sub < 4; ++sub)
            *(ushort4*)&sP[w][ln][16*sub + 4*g] =
                make_ushort4(f2bf(lg[4*sub+0]), f2bf(lg[4*sub+1]),
                             f2bf(lg[4*sub+2]), f2bf(lg[4*sub+3]));

        // ---- rescale O, then PV: O^T += V^T · P^T
#pragma unroll
        for (int i = 0; i < 4; ++i) accO[i] *= sc;
#pragma unroll
        for (int ks = 0; ks < 2; ++ks) {
            v8s pp = *(const v8s*)&sP[w][ln][32*ks + 8*g];
#pragma unroll
            for (int sub = 0; sub < 4; ++sub) {
                v8s vh = *(const v8s*)&sVh[16*sub + ln][32*ks + 8*g];
                accO[sub] = __builtin_amdgcn_mfma_f32_16x16x32_bf16(vh, pp, accO[sub], 0, 0, 0);
            }
        }
    }

    // ---- epilogue: unnormalized partial O^T + (M, L)
    long ob = ((long)bid*64 + (w*16 + ln)) * 64;
#pragma unroll
    for (int sub = 0; sub < 4; ++sub)
        *(f32x4*)&Opart[ob + 16*sub + 4*g] = accO[sub];
    if (g == 0) {
        Mp[bid*64 + w*16 + ln] = M;
        Lp[bid*64 + w*16 + ln] = L;
    }
}

// ---------------------------------------------------------------------------
// Kernel 4: merge the two m-halves (flash combine) + normalize.
// ---------------------------------------------------------------------------
__global__ __launch_bounds__(256) void combine_kernel(
    const float* __restrict__ Opart, const float* __restrict__ Mp,
    const float* __restrict__ Lp, float* __restrict__ out)
{
    int idx = blockIdx.x * 256 + threadIdx.x;   // 262144 float4-quads
    int kq = idx & 15;
    int row = idx >> 4;                          // b*2048 + n
    int b = row >> 11, n = row & 2047;
    int nt = n >> 6, r = n & 63;
    int bid0 = ((nt*2 + 0) << 3) | b;
    int bid1 = bid0 + 8;
    float M0 = Mp[bid0*64 + r], L0 = Lp[bid0*64 + r];
    float M1 = Mp[bid1*64 + r], L1 = Lp[bid1*64 + r];
    float Mx = fmaxf(M0, M1);
    float e0 = __expf(M0 - Mx), e1 = __expf(M1 - Mx);
    float4 O0 = *(const float4*)&Opart[((long)bid0*64 + r)*64 + 4*kq];
    float4 O1 = *(const float4*)&Opart[((long)bid1*64 + r)*64 + 4*kq];
    float inv = 1.0f / (L0*e0 + L1*e1);
    float4 o;
    o.x = (O0.x*e0 + O1.x*e1) * inv;
    o.y = (O0.y*e0 + O1.y*e1) * inv;
    o.z = (O0.z*e0 + O1.z*e1) * inv;
    o.w = (O0.w*e0 + O1.w*e1) * inv;
    *(float4*)&out[(long)row*64 + 4*kq] = o;
}

// ---------------------------------------------------------------------------
extern "C" void kernel_launch(void* const* d_in, const int* in_sizes, int n_in,
                              void* d_out, int out_size, void* d_ws, size_t ws_size,
                              hipStream_t stream) {
    const float* src  = (const float*)d_in[0];
    const float* bias = (const float*)d_in[1];
    const float* mult = (const float*)d_in[2];
    const float* Wr   = (const float*)d_in[3];
    const float* Cc   = (const float*)d_in[4];
    const float* logp = (const float*)d_in[5];
    const float* Wq   = (const float*)d_in[6];
    const float* Wk   = (const float*)d_in[7];
    const float* Wv   = (const float*)d_in[8];
    const float* sp   = (const float*)d_in[9];
    float* outp = (float*)d_out;

    const size_t QKV_E = (size_t)NB * N_SEQ * KD;       // 1048576
    ushort* wsu = (ushort*)d_ws;
    ushort* Bm = wsu;                                   // 2048*2048 shorts
    ushort* Qh = wsu + (size_t)N_SEQ * N_SEQ;
    ushort* Ql = Qh + QKV_E;
    ushort* Kh = Ql + QKV_E;
    ushort* Kl = Kh + QKV_E;
    ushort* Vh = Kl + QKV_E;
    float* Of  = (float*)(Vh + QKV_E);                  // 512*64*64 floats
    float* Mp  = Of + (size_t)512 * 64 * 64;
    float* Lp  = Mp + (size_t)512 * 64;
    // Table overlays Of: used only by tbuild/ftheta (both complete before
    // attn writes Opart on the same stream).
    float2* Tp = (float2*)Of;                           // 512*512 float2 = 2MB

    tbuild_kernel<<<(TG*TG)/256, 256, 0, stream>>>(Wr, Cc, Tp);
    ftheta_kernel<<<(N_SEQ*(long)N_SEQ)/512, 256, 0, stream>>>(bias, Tp, logp, Bm);
    qkv_kernel<<<(NB*N_SEQ)/32, 256, 0, stream>>>(src, Wq, Wk, Wv, Qh, Ql, Kh, Kl, Vh);
    attn_mfma_kernel<<<512, 256, 0, stream>>>(Qh, Ql, Kh, Kl, Vh, Bm, mult, sp, Of, Mp, Lp);
    combine_kernel<<<1024, 256, 0, stream>>>(Of, Mp, Lp, outp);
}

// Round 5
// 181.349 us; speedup vs baseline: 1.9307x; 1.0589x over previous
//
#include <hip/hip_runtime.h>
#include <hip/hip_bf16.h>

#define N_SEQ 2048
#define NB 8
#define DM 512
#define KD 64
#define NF 70

#define TG 512                   // table grid
#define TRANGE 6.5f              // table covers [-TRANGE, TRANGE]
#define TSCL (511.0f / 13.0f)    // (TG-1) / (2*TRANGE)
#define TOFS (6.5f * TSCL)       // 255.5

typedef float f32x4 __attribute__((ext_vector_type(4)));
typedef float f32x2 __attribute__((ext_vector_type(2)));
typedef short v8s  __attribute__((ext_vector_type(8)));

__device__ __forceinline__ ushort f2bf(float x) {
    uint u = __float_as_uint(x);
    return (ushort)((u + 0x7FFFu + ((u >> 16) & 1u)) >> 16);
}
__device__ __forceinline__ float bf2f(ushort h) {
    return __uint_as_float(((uint)h) << 16);
}

// ---------------------------------------------------------------------------
// Kernel 0: build table  g(x,y) = sum_f C_f*sqrt2*sin(x*w0+y*w1+pi/4)
// paired layout Tp[j*TG+i] = (g(x_i,y_j), g(x_{i+1},y_j)).
// ---------------------------------------------------------------------------
__global__ __launch_bounds__(256) void tbuild_kernel(
    const float* __restrict__ Wr, const float* __restrict__ Cc,
    float2* __restrict__ Tp)
{
    const float SQ2 = 1.41421356237309504880f;
    const float R2PI = 0.15915494309189533577f;
    int idx = blockIdx.x * 256 + threadIdx.x;      // TG*TG threads
    int j = idx >> 9, i = idx & (TG - 1);
    const float h = 2.0f * TRANGE / (TG - 1);
    float y  = -TRANGE + j * h;
    float x0 = -TRANGE + i * h;
    float x1 = -TRANGE + min(i + 1, TG - 1) * h;
    float g0 = 0.f, g1 = 0.f;
    for (int f = 0; f < NF; ++f) {
        float w0 = Wr[2*f] * R2PI, w1 = Wr[2*f+1] * R2PI, cf = Cc[f];
        float base = fmaf(y, w1, 0.125f);
        float k0 = __builtin_amdgcn_fractf(fmaf(x0, w0, base));
        float k1 = __builtin_amdgcn_fractf(fmaf(x1, w0, base));
        g0 = fmaf(cf, __builtin_amdgcn_sinf(k0), g0);
        g1 = fmaf(cf, __builtin_amdgcn_sinf(k1), g1);
    }
    Tp[idx] = make_float2(g0 * SQ2, g1 * SQ2);
}

// ---------------------------------------------------------------------------
// Kernel 1: f_theta via bilinear table lookups -> Bmat bf16.
// ---------------------------------------------------------------------------
__device__ __forceinline__ float tlookup(const float2* __restrict__ Tp,
                                         float x, float y)
{
    float u = fmaf(x, TSCL, TOFS);
    float v = fmaf(y, TSCL, TOFS);
    u = fminf(fmaxf(u, 0.0f), 510.999f);
    v = fminf(fmaxf(v, 0.0f), 510.999f);
    int iu = (int)u, iv = (int)v;
    float fu = __builtin_amdgcn_fractf(u);
    float fv = __builtin_amdgcn_fractf(v);
    int base = iv * TG + iu;
    float2 r0 = Tp[base];
    float2 r1 = Tp[base + TG];
    float t0 = fmaf(fu, r0.y - r0.x, r0.x);
    float t1 = fmaf(fu, r1.y - r1.x, r1.x);
    return fmaf(fv, t1 - t0, t0);
}

__global__ __launch_bounds__(256) void ftheta_kernel(
    const float* __restrict__ bias, const float2* __restrict__ Tp,
    const float* __restrict__ logp, ushort* __restrict__ Bm)
{
    int tid = threadIdx.x;
    long i0 = (long)blockIdx.x * 512 + tid;
    long i1 = i0 + 256;
    float4 a = ((const float4*)bias)[i0];
    float4 b = ((const float4*)bias)[i1];
    float gA1 = tlookup(Tp, a.x, a.y);
    float gA2 = tlookup(Tp, a.z, a.w);
    float gB1 = tlookup(Tp, b.x, b.y);
    float gB2 = tlookup(Tp, b.z, b.w);
    float s0 = fabsf(gA1 - gA2) + 1e-6f;
    float s1 = fabsf(gB1 - gB2) + 1e-6f;
    float p = __expf(logp[0]);
    p = fminf(fmaxf(p, 0.5f), 3.0f);
    if (p == 1.0f) {
        Bm[i0] = f2bf(__expf(-s0));
        Bm[i1] = f2bf(__expf(-s1));
    } else {
        Bm[i0] = f2bf(__expf(-__powf(s0, p)));
        Bm[i1] = f2bf(__expf(-__powf(s1, p)));
    }
}

// ---------------------------------------------------------------------------
// Kernel 2: QKV projection. Emits hi/lo-split bf16 Q,K and TRANSPOSED bf16 V
// (VhT[b][kv][n], so attention stages V^T with coalesced uint4 rows).
// ---------------------------------------------------------------------------
__global__ __launch_bounds__(256) void qkv_kernel(
    const float* __restrict__ src, const float* __restrict__ Wq,
    const float* __restrict__ Wk, const float* __restrict__ Wv,
    ushort* __restrict__ Qh, ushort* __restrict__ Ql,
    ushort* __restrict__ Kh, ushort* __restrict__ Kl,
    ushort* __restrict__ VhT)
{
    __shared__ float sS[32][68];
    __shared__ float sW[192][65];
    __shared__ ushort sVT2[64][40];   // 80B row stride (16B-aligned)
    int tid = threadIdx.x;
    long bn0 = (long)blockIdx.x * 32;
    int c = tid & 63, wg = tid >> 6;
    float aQ[8], aK[8], aV[8];
#pragma unroll
    for (int r = 0; r < 8; ++r) { aQ[r] = 0.f; aK[r] = 0.f; aV[r] = 0.f; }

    for (int ch = 0; ch < 8; ++ch) {
        int d0 = ch * 64;
        __syncthreads();
        {
            int s1 = tid;       int r1 = s1 >> 4, q1 = s1 & 15;
            *(float4*)&sS[r1][4*q1] =
                *(const float4*)&src[(bn0 + r1)*DM + d0 + 4*q1];
            int s2 = tid + 256; int r2 = s2 >> 4, q2 = s2 & 15;
            *(float4*)&sS[r2][4*q2] =
                *(const float4*)&src[(bn0 + r2)*DM + d0 + 4*q2];
        }
        {
#pragma unroll
            for (int j = 0; j < 12; ++j) {
                int s = tid + j*256; int cw = s >> 4; int k4 = s & 15;
                const float* Wp = (cw < 64) ? Wq : (cw < 128 ? Wk : Wv);
                int cc = cw & 63;
                float4 w4 = *(const float4*)&Wp[(long)cc*DM + d0 + 4*k4];
                sW[cw][4*k4+0] = w4.x; sW[cw][4*k4+1] = w4.y;
                sW[cw][4*k4+2] = w4.z; sW[cw][4*k4+3] = w4.w;
            }
        }
        __syncthreads();
#pragma unroll 4
        for (int d = 0; d < 64; ++d) {
            float wq = sW[c][d], wk = sW[64+c][d], wv = sW[128+c][d];
#pragma unroll
            for (int r = 0; r < 8; ++r) {
                float sv = sS[wg + 4*r][d];
                aQ[r] = fmaf(sv, wq, aQ[r]);
                aK[r] = fmaf(sv, wk, aK[r]);
                aV[r] = fmaf(sv, wv, aV[r]);
            }
        }
    }
#pragma unroll
    for (int r = 0; r < 8; ++r) {
        long row = bn0 + wg + 4*r;
        ushort qh = f2bf(aQ[r]); float qhf = bf2f(qh);
        ushort kh = f2bf(aK[r]); float khf = bf2f(kh);
        Qh[row*KD + c] = qh;
        Ql[row*KD + c] = f2bf(aQ[r] - qhf);
        Kh[row*KD + c] = kh;
        Kl[row*KD + c] = f2bf(aK[r] - khf);
        sVT2[c][wg + 4*r] = f2bf(aV[r]);     // transpose via LDS
    }
    __syncthreads();
    {
        int kv = tid >> 2, o8 = (tid & 3) * 8;
        int bb = (int)(bn0 >> 11), nn0 = (int)(bn0 & 2047);
        long vbase = ((long)bb*KD + kv)*N_SEQ + nn0;
        *(uint4*)&VhT[vbase + o8] = *(uint4*)&sVT2[kv][o8];
    }
}

// ---------------------------------------------------------------------------
// Kernel 3: MFMA flash attention, m-split in 4 quarters.
// Block: 256 thr (4 waves), 64 n-rows. Q hi/lo in REGISTERS (loop-invariant).
// LDS only K hi/lo + V^T + P = 37KB -> 4 blocks/CU (16 waves) for latency.
// Swapped QK^T: S^T = K*Q^T, lane owns q-row n=lane&15 (softmax lane-local).
// bid = ((nt*4+p)<<3)|b  so batch == XCD (K/V L2-resident).
// ---------------------------------------------------------------------------
__global__ __launch_bounds__(256, 4) void attn_mfma_kernel(
    const ushort* __restrict__ Qh, const ushort* __restrict__ Ql,
    const ushort* __restrict__ Kh, const ushort* __restrict__ Kl,
    const ushort* __restrict__ VhT, const ushort* __restrict__ Bm,
    const float* __restrict__ mult, const float* __restrict__ sp,
    ushort* __restrict__ Opart, float* __restrict__ Mp, float* __restrict__ Lp)
{
    __shared__ ushort sKh[64][72], sKl[64][72];
    __shared__ ushort sVT[64][72];              // V^T: [kv][m]
    __shared__ ushort sP[4][16][72];            // per wave: [n][m]

    int tid = threadIdx.x;
    int lane = tid & 63, w = tid >> 6;
    int g = lane >> 4, ln = lane & 15;
    int bid = blockIdx.x;
    int b = bid & 7, rest = bid >> 3, p = rest & 3, nt = rest >> 2;
    int n0 = nt * 64;

    // ---- Q (hi/lo) into registers: lane (g,ln) needs row n0+w*16+ln,
    //      k-slices 8g and 32+8g.
    int qrow = n0 + w*16 + ln;
    long qoff = ((long)b*N_SEQ + qrow)*KD + 8*g;
    v8s qh0 = *(const v8s*)&Qh[qoff];
    v8s qh1 = *(const v8s*)&Qh[qoff + 32];
    v8s ql0 = *(const v8s*)&Ql[qoff];
    v8s ql1 = *(const v8s*)&Ql[qoff + 32];

    float s  = sp[0];
    float qs = 0.125f * s;
    float M = -1e30f, L = 0.f;
    f32x4 accO[4];
#pragma unroll
    for (int i = 0; i < 4; ++i) accO[i] = {0.f, 0.f, 0.f, 0.f};

    long brow = (long)qrow * N_SEQ;
    long urow = ((long)b*N_SEQ + qrow) * N_SEQ;
    long vtb  = (long)b*KD*N_SEQ;

    for (int mt = 0; mt < 8; ++mt) {
        int m0 = p*512 + mt*64;
        long kbase = ((long)b*N_SEQ + m0) * KD;
        __syncthreads();                     // prev-iter reads of sK/sVT done
        // ---- stage K hi/lo + V^T, all coalesced uint4 rows
#pragma unroll
        for (int j = 0; j < 2; ++j) {
            int slot = tid + j*256;
            int row = slot >> 3, c8 = slot & 7;
            *(uint4*)&sKh[row][8*c8] = *(const uint4*)&Kh[kbase + (long)row*KD + 8*c8];
            *(uint4*)&sKl[row][8*c8] = *(const uint4*)&Kl[kbase + (long)row*KD + 8*c8];
            *(uint4*)&sVT[row][8*c8] = *(const uint4*)&VhT[vtb + (long)row*N_SEQ + m0 + 8*c8];
        }
        // ---- bias / multiplier for this lane's 16 logits
        ushort4 Bq[4]; float4 Uq[4];
#pragma unroll
        for (int sub = 0; sub < 4; ++sub) {
            Bq[sub] = *(const ushort4*)&Bm[brow + m0 + 16*sub + 4*g];
            Uq[sub] = *(const float4*)&mult[urow + m0 + 16*sub + 4*g];
        }
        __syncthreads();

        // ---- QK^T (swapped): S[sub] = K_sub * Q^T, split-bf16 3-term
        f32x4 S[4];
#pragma unroll
        for (int i = 0; i < 4; ++i) S[i] = {0.f, 0.f, 0.f, 0.f};
#pragma unroll
        for (int ks = 0; ks < 2; ++ks) {
            v8s qh = ks ? qh1 : qh0;
            v8s ql = ks ? ql1 : ql0;
#pragma unroll
            for (int sub = 0; sub < 4; ++sub) {
                v8s kh = *(const v8s*)&sKh[16*sub + ln][32*ks + 8*g];
                v8s kl = *(const v8s*)&sKl[16*sub + ln][32*ks + 8*g];
                S[sub] = __builtin_amdgcn_mfma_f32_16x16x32_bf16(kh, qh, S[sub], 0, 0, 0);
                S[sub] = __builtin_amdgcn_mfma_f32_16x16x32_bf16(kl, qh, S[sub], 0, 0, 0);
                S[sub] = __builtin_amdgcn_mfma_f32_16x16x32_bf16(kh, ql, S[sub], 0, 0, 0);
            }
        }

        // ---- logits + online softmax (lane-local row n = ln)
        float lg[16]; float mx = -1e30f;
#pragma unroll
        for (int sub = 0; sub < 4; ++sub) {
            float b0 = bf2f(Bq[sub].x), b1 = bf2f(Bq[sub].y);
            float b2 = bf2f(Bq[sub].z), b3 = bf2f(Bq[sub].w);
            lg[4*sub+0] = (S[sub][0] + b0) * Uq[sub].x * qs;
            lg[4*sub+1] = (S[sub][1] + b1) * Uq[sub].y * qs;
            lg[4*sub+2] = (S[sub][2] + b2) * Uq[sub].z * qs;
            lg[4*sub+3] = (S[sub][3] + b3) * Uq[sub].w * qs;
            mx = fmaxf(mx, fmaxf(fmaxf(lg[4*sub+0], lg[4*sub+1]),
                                 fmaxf(lg[4*sub+2], lg[4*sub+3])));
        }
        mx = fmaxf(mx, __shfl_xor(mx, 16));
        mx = fmaxf(mx, __shfl_xor(mx, 32));
        float Mn = fmaxf(M, mx);
        float sc = __expf(M - Mn);
        float ps = 0.f;
#pragma unroll
        for (int i = 0; i < 16; ++i) {
            float e = __expf(lg[i] - Mn);
            lg[i] = e; ps += e;
        }
        ps += __shfl_xor(ps, 16);
        ps += __shfl_xor(ps, 32);
        L = L * sc + ps; M = Mn;

        // ---- P -> bf16 in LDS (wave-private, no barrier needed)
#pragma unroll
        for (int sub = 0; sub < 4; ++sub)
            *(ushort4*)&sP[w][ln][16*sub + 4*g] =
                make_ushort4(f2bf(lg[4*sub+0]), f2bf(lg[4*sub+1]),
                             f2bf(lg[4*sub+2]), f2bf(lg[4*sub+3]));

        // ---- rescale O, then PV: O^T += V^T * P^T
#pragma unroll
        for (int i = 0; i < 4; ++i) accO[i] *= sc;
#pragma unroll
        for (int ks = 0; ks < 2; ++ks) {
            v8s pp = *(const v8s*)&sP[w][ln][32*ks + 8*g];
#pragma unroll
            for (int sub = 0; sub < 4; ++sub) {
                v8s vh = *(const v8s*)&sVT[16*sub + ln][32*ks + 8*g];
                accO[sub] = __builtin_amdgcn_mfma_f32_16x16x32_bf16(vh, pp, accO[sub], 0, 0, 0);
            }
        }
    }

    // ---- epilogue: unnormalized partial O^T (bf16) + (M, L)
    long ob = ((long)bid*64 + (w*16 + ln)) * 64;
#pragma unroll
    for (int sub = 0; sub < 4; ++sub)
        *(ushort4*)&Opart[ob + 16*sub + 4*g] =
            make_ushort4(f2bf(accO[sub][0]), f2bf(accO[sub][1]),
                         f2bf(accO[sub][2]), f2bf(accO[sub][3]));
    if (g == 0) {
        Mp[bid*64 + w*16 + ln] = M;
        Lp[bid*64 + w*16 + ln] = L;
    }
}

// ---------------------------------------------------------------------------
// Kernel 4: merge the four m-quarters (flash combine) + normalize.
// ---------------------------------------------------------------------------
__global__ __launch_bounds__(256) void combine_kernel(
    const ushort* __restrict__ Opart, const float* __restrict__ Mp,
    const float* __restrict__ Lp, float* __restrict__ out)
{
    int idx = blockIdx.x * 256 + threadIdx.x;   // 262144 float4-quads
    int kq = idx & 15;
    int row = idx >> 4;                          // b*2048 + n
    int b = row >> 11, n = row & 2047;
    int nt = n >> 6, r = n & 63;
    int bid0 = ((nt*4) << 3) | b;                // +8 per quarter
    float Mq[4], Lq[4];
#pragma unroll
    for (int p = 0; p < 4; ++p) {
        Mq[p] = Mp[(bid0 + 8*p)*64 + r];
        Lq[p] = Lp[(bid0 + 8*p)*64 + r];
    }
    float Mx = fmaxf(fmaxf(Mq[0], Mq[1]), fmaxf(Mq[2], Mq[3]));
    float4 acc = make_float4(0.f, 0.f, 0.f, 0.f);
    float Ls = 0.f;
#pragma unroll
    for (int p = 0; p < 4; ++p) {
        float e = __expf(Mq[p] - Mx);
        Ls += Lq[p] * e;
        ushort4 o = *(const ushort4*)&Opart[((long)(bid0 + 8*p)*64 + r)*64 + 4*kq];
        acc.x = fmaf(e, bf2f(o.x), acc.x);
        acc.y = fmaf(e, bf2f(o.y), acc.y);
        acc.z = fmaf(e, bf2f(o.z), acc.z);
        acc.w = fmaf(e, bf2f(o.w), acc.w);
    }
    float inv = 1.0f / Ls;
    float4 o;
    o.x = acc.x * inv; o.y = acc.y * inv;
    o.z = acc.z * inv; o.w = acc.w * inv;
    *(float4*)&out[(long)row*64 + 4*kq] = o;
}

// ---------------------------------------------------------------------------
extern "C" void kernel_launch(void* const* d_in, const int* in_sizes, int n_in,
                              void* d_out, int out_size, void* d_ws, size_t ws_size,
                              hipStream_t stream) {
    const float* src  = (const float*)d_in[0];
    const float* bias = (const float*)d_in[1];
    const float* mult = (const float*)d_in[2];
    const float* Wr   = (const float*)d_in[3];
    const float* Cc   = (const float*)d_in[4];
    const float* logp = (const float*)d_in[5];
    const float* Wq   = (const float*)d_in[6];
    const float* Wk   = (const float*)d_in[7];
    const float* Wv   = (const float*)d_in[8];
    const float* sp   = (const float*)d_in[9];
    float* outp = (float*)d_out;

    const size_t QKV_E = (size_t)NB * N_SEQ * KD;       // 1048576
    ushort* wsu = (ushort*)d_ws;
    ushort* Bm  = wsu;                                  // 8.39 MB
    ushort* Qh  = wsu + (size_t)N_SEQ * N_SEQ;          // 2.10 MB each
    ushort* Ql  = Qh + QKV_E;
    ushort* Kh  = Ql + QKV_E;
    ushort* Kl  = Kh + QKV_E;
    ushort* VhT = Kl + QKV_E;
    ushort* Opart = VhT + QKV_E;                        // 1024*64*64 bf16 = 8.39 MB
    float* Mp = (float*)(Opart + (size_t)1024 * 64 * 64);
    float* Lp = Mp + (size_t)1024 * 64;
    // Table overlays Opart (tbuild/ftheta complete before attn writes it).
    float2* Tp = (float2*)Opart;                        // 2 MB

    tbuild_kernel<<<(TG*TG)/256, 256, 0, stream>>>(Wr, Cc, Tp);
    ftheta_kernel<<<(N_SEQ*(long)N_SEQ)/512, 256, 0, stream>>>(bias, Tp, logp, Bm);
    qkv_kernel<<<(NB*N_SEQ)/32, 256, 0, stream>>>(src, Wq, Wk, Wv, Qh, Ql, Kh, Kl, VhT);
    attn_mfma_kernel<<<1024, 256, 0, stream>>>(Qh, Ql, Kh, Kl, VhT, Bm, mult, sp,
                                               Opart, Mp, Lp);
    combine_kernel<<<1024, 256, 0, stream>>>(Opart, Mp, Lp, outp);
}

// Round 6
// 180.602 us; speedup vs baseline: 1.9386x; 1.0041x over previous
//
#include <hip/hip_runtime.h>
#include <hip/hip_bf16.h>

#define N_SEQ 2048
#define NB 8
#define DM 512
#define KD 64
#define NF 70

#define TG 512                   // table grid
#define TRANGE 6.5f              // table covers [-TRANGE, TRANGE]
#define TSCL (511.0f / 13.0f)    // (TG-1) / (2*TRANGE)
#define TOFS (6.5f * TSCL)       // 255.5

typedef float f32x4 __attribute__((ext_vector_type(4)));
typedef short v8s  __attribute__((ext_vector_type(8)));

__device__ __forceinline__ ushort f2bf(float x) {
    uint u = __float_as_uint(x);
    return (ushort)((u + 0x7FFFu + ((u >> 16) & 1u)) >> 16);
}
__device__ __forceinline__ float bf2f(ushort h) {
    return __uint_as_float(((uint)h) << 16);
}

// ---------------------------------------------------------------------------
// Kernel 0: build table  g(x,y) = sum_f C_f*sqrt2*sin(x*w0+y*w1+pi/4)
// paired layout Tp[j*TG+i] = (g(x_i,y_j), g(x_{i+1},y_j)).
// ---------------------------------------------------------------------------
__global__ __launch_bounds__(256) void tbuild_kernel(
    const float* __restrict__ Wr, const float* __restrict__ Cc,
    float2* __restrict__ Tp)
{
    const float SQ2 = 1.41421356237309504880f;
    const float R2PI = 0.15915494309189533577f;
    int idx = blockIdx.x * 256 + threadIdx.x;      // TG*TG threads
    int j = idx >> 9, i = idx & (TG - 1);
    const float h = 2.0f * TRANGE / (TG - 1);
    float y  = -TRANGE + j * h;
    float x0 = -TRANGE + i * h;
    float x1 = -TRANGE + min(i + 1, TG - 1) * h;
    float g0 = 0.f, g1 = 0.f;
    for (int f = 0; f < NF; ++f) {
        float w0 = Wr[2*f] * R2PI, w1 = Wr[2*f+1] * R2PI, cf = Cc[f];
        float base = fmaf(y, w1, 0.125f);
        float k0 = __builtin_amdgcn_fractf(fmaf(x0, w0, base));
        float k1 = __builtin_amdgcn_fractf(fmaf(x1, w0, base));
        g0 = fmaf(cf, __builtin_amdgcn_sinf(k0), g0);
        g1 = fmaf(cf, __builtin_amdgcn_sinf(k1), g1);
    }
    Tp[idx] = make_float2(g0 * SQ2, g1 * SQ2);
}

// ---------------------------------------------------------------------------
// Kernel 1: f_theta via bilinear table lookups -> Bmat bf16.
// ---------------------------------------------------------------------------
__device__ __forceinline__ float tlookup(const float2* __restrict__ Tp,
                                         float x, float y)
{
    float u = fmaf(x, TSCL, TOFS);
    float v = fmaf(y, TSCL, TOFS);
    u = fminf(fmaxf(u, 0.0f), 510.999f);
    v = fminf(fmaxf(v, 0.0f), 510.999f);
    int iu = (int)u, iv = (int)v;
    float fu = __builtin_amdgcn_fractf(u);
    float fv = __builtin_amdgcn_fractf(v);
    int base = iv * TG + iu;
    float2 r0 = Tp[base];
    float2 r1 = Tp[base + TG];
    float t0 = fmaf(fu, r0.y - r0.x, r0.x);
    float t1 = fmaf(fu, r1.y - r1.x, r1.x);
    return fmaf(fv, t1 - t0, t0);
}

__global__ __launch_bounds__(256) void ftheta_kernel(
    const float* __restrict__ bias, const float2* __restrict__ Tp,
    const float* __restrict__ logp, ushort* __restrict__ Bm)
{
    int tid = threadIdx.x;
    long i0 = (long)blockIdx.x * 512 + tid;
    long i1 = i0 + 256;
    float4 a = ((const float4*)bias)[i0];
    float4 b = ((const float4*)bias)[i1];
    float gA1 = tlookup(Tp, a.x, a.y);
    float gA2 = tlookup(Tp, a.z, a.w);
    float gB1 = tlookup(Tp, b.x, b.y);
    float gB2 = tlookup(Tp, b.z, b.w);
    float s0 = fabsf(gA1 - gA2) + 1e-6f;
    float s1 = fabsf(gB1 - gB2) + 1e-6f;
    float p = __expf(logp[0]);
    p = fminf(fmaxf(p, 0.5f), 3.0f);
    if (p == 1.0f) {
        Bm[i0] = f2bf(__expf(-s0));
        Bm[i1] = f2bf(__expf(-s1));
    } else {
        Bm[i0] = f2bf(__expf(-__powf(s0, p)));
        Bm[i1] = f2bf(__expf(-__powf(s1, p)));
    }
}

// ---------------------------------------------------------------------------
// Kernel 2: QKV projection via MFMA (bf16 x bf16, fp32 acc).
// 512 blocks x 32 rows; 4 waves: wave(wr,wc) -> rows 16*wr, cols 96*wc.
// Stages src-chunk + all-192 W rows per k-chunk of 64 in LDS (bf16).
// Emits hi/lo-split bf16 Q,K and transposed bf16 V (VhT[b][kv][n]).
// ---------------------------------------------------------------------------
__global__ __launch_bounds__(256) void qkv_kernel(
    const float* __restrict__ src, const float* __restrict__ Wq,
    const float* __restrict__ Wk, const float* __restrict__ Wv,
    ushort* __restrict__ Qh, ushort* __restrict__ Ql,
    ushort* __restrict__ Kh, ushort* __restrict__ Kl,
    ushort* __restrict__ VhT)
{
    __shared__ ushort sS[32][72];     // src rows (bf16), one 64-k chunk
    __shared__ ushort sW[192][72];    // Wq|Wk|Wv rows (bf16), one 64-k chunk
    int tid = threadIdx.x;
    int lane = tid & 63, w = tid >> 6;
    int wr = w >> 1, wc = w & 1;
    int g = lane >> 4, ln = lane & 15;
    int row0 = blockIdx.x * 32;

    f32x4 acc[6];
#pragma unroll
    for (int t = 0; t < 6; ++t) acc[t] = {0.f, 0.f, 0.f, 0.f};

    for (int kc = 0; kc < 8; ++kc) {
        int k0 = kc * 64;
        __syncthreads();
        {   // stage src chunk: 32x64, 1 slot (8 elems) per thread
            int r = tid >> 3, c8 = (tid & 7) * 8;
            float4 f0 = *(const float4*)&src[(long)(row0 + r)*DM + k0 + c8];
            float4 f1 = *(const float4*)&src[(long)(row0 + r)*DM + k0 + c8 + 4];
            *(ushort4*)&sS[r][c8] =
                make_ushort4(f2bf(f0.x), f2bf(f0.y), f2bf(f0.z), f2bf(f0.w));
            *(ushort4*)&sS[r][c8+4] =
                make_ushort4(f2bf(f1.x), f2bf(f1.y), f2bf(f1.z), f2bf(f1.w));
        }
        {   // stage W chunk: 192x64, 6 slots per thread
#pragma unroll
            for (int j = 0; j < 6; ++j) {
                int slot = tid + j*256;
                int r = slot >> 3, c8 = (slot & 7) * 8;
                const float* Wp = (r < 64) ? Wq : (r < 128 ? Wk : Wv);
                int rr = r & 63;
                float4 f0 = *(const float4*)&Wp[(long)rr*DM + k0 + c8];
                float4 f1 = *(const float4*)&Wp[(long)rr*DM + k0 + c8 + 4];
                *(ushort4*)&sW[r][c8] =
                    make_ushort4(f2bf(f0.x), f2bf(f0.y), f2bf(f0.z), f2bf(f0.w));
                *(ushort4*)&sW[r][c8+4] =
                    make_ushort4(f2bf(f1.x), f2bf(f1.y), f2bf(f1.z), f2bf(f1.w));
            }
        }
        __syncthreads();
#pragma unroll
        for (int kw = 0; kw < 2; ++kw) {
            v8s bsrc = *(const v8s*)&sS[16*wr + ln][32*kw + 8*g];
#pragma unroll
            for (int t = 0; t < 6; ++t) {
                v8s aw = *(const v8s*)&sW[96*wc + 16*t + ln][32*kw + 8*g];
                acc[t] = __builtin_amdgcn_mfma_f32_16x16x32_bf16(aw, bsrc, acc[t], 0, 0, 0);
            }
        }
    }
    // epilogue: lane (g,ln) holds O[n=row0+16*wr+ln][c=96*wc+16*t+4*g+i]
    int n = row0 + 16*wr + ln;
    int bb = n >> 11, nn = n & 2047;
#pragma unroll
    for (int t = 0; t < 6; ++t) {
#pragma unroll
        for (int i = 0; i < 4; ++i) {
            int c = 96*wc + 16*t + 4*g + i;
            float v = acc[t][i];
            if (c < 64) {
                ushort h = f2bf(v);
                Qh[(long)n*KD + c] = h;
                Ql[(long)n*KD + c] = f2bf(v - bf2f(h));
            } else if (c < 128) {
                int cc = c - 64;
                ushort h = f2bf(v);
                Kh[(long)n*KD + cc] = h;
                Kl[(long)n*KD + cc] = f2bf(v - bf2f(h));
            } else {
                int kv = c - 128;
                VhT[((long)bb*KD + kv)*N_SEQ + nn] = f2bf(v);
            }
        }
    }
}

// ---------------------------------------------------------------------------
// Kernel 3: MFMA flash attention, m-split in 4 quarters, reg-staged prefetch.
// Block: 256 thr (4 waves), 64 n-rows. Q hi/lo in registers (loop-invariant).
// Pipeline: tile t+1 global->regs issued right after post-stage barrier,
// ds_write at top of next iter (T14); setprio around MFMA clusters (T5).
// bid = ((nt*4+p)<<3)|b  so batch == XCD (K/V L2-resident).
// ---------------------------------------------------------------------------
__global__ __launch_bounds__(256, 4) void attn_mfma_kernel(
    const ushort* __restrict__ Qh, const ushort* __restrict__ Ql,
    const ushort* __restrict__ Kh, const ushort* __restrict__ Kl,
    const ushort* __restrict__ VhT, const ushort* __restrict__ Bm,
    const float* __restrict__ mult, const float* __restrict__ sp,
    ushort* __restrict__ Opart, float* __restrict__ Mp, float* __restrict__ Lp)
{
    __shared__ ushort sKh[64][72], sKl[64][72];
    __shared__ ushort sVT[64][72];              // V^T: [kv][m]
    __shared__ ushort sP[4][16][72];            // per wave: [n][m]

    int tid = threadIdx.x;
    int lane = tid & 63, w = tid >> 6;
    int g = lane >> 4, ln = lane & 15;
    int bid = blockIdx.x;
    int b = bid & 7, rest = bid >> 3, p = rest & 3, nt = rest >> 2;
    int n0 = nt * 64;

    // ---- Q (hi/lo) into registers
    int qrow = n0 + w*16 + ln;
    long qoff = ((long)b*N_SEQ + qrow)*KD + 8*g;
    v8s qh0 = *(const v8s*)&Qh[qoff];
    v8s qh1 = *(const v8s*)&Qh[qoff + 32];
    v8s ql0 = *(const v8s*)&Ql[qoff];
    v8s ql1 = *(const v8s*)&Ql[qoff + 32];

    float s  = sp[0];
    float qs = 0.125f * s;
    float M = -1e30f, L = 0.f;
    f32x4 accO[4];
#pragma unroll
    for (int i = 0; i < 4; ++i) accO[i] = {0.f, 0.f, 0.f, 0.f};

    long brow = (long)qrow * N_SEQ;
    long urow = ((long)b*N_SEQ + qrow) * N_SEQ;
    long vtb  = (long)b*KD*N_SEQ;
    long kbB  = (long)b*N_SEQ*KD;

    // staging slots for this thread
    int srow0 = tid >> 3,        sc8_0 = (tid & 7) * 8;
    int srow1 = (tid + 256) >> 3, sc8_1 = (tid & 7) * 8;   // rows 0..31 / 32..63

    // ---- prologue: prefetch tile 0 into regs
    uint4 rKh0, rKh1, rKl0, rKl1, rVT0, rVT1;
    {
        int m0 = p*512;
        rKh0 = *(const uint4*)&Kh[kbB + (long)(m0+srow0)*KD + sc8_0];
        rKh1 = *(const uint4*)&Kh[kbB + (long)(m0+srow1)*KD + sc8_1];
        rKl0 = *(const uint4*)&Kl[kbB + (long)(m0+srow0)*KD + sc8_0];
        rKl1 = *(const uint4*)&Kl[kbB + (long)(m0+srow1)*KD + sc8_1];
        rVT0 = *(const uint4*)&VhT[vtb + (long)srow0*N_SEQ + m0 + sc8_0];
        rVT1 = *(const uint4*)&VhT[vtb + (long)srow1*N_SEQ + m0 + sc8_1];
    }

    for (int mt = 0; mt < 8; ++mt) {
        int m0 = p*512 + mt*64;
        __syncthreads();                     // prev compute done reading LDS
        // ---- ds_write staged regs
        *(uint4*)&sKh[srow0][sc8_0] = rKh0;
        *(uint4*)&sKh[srow1][sc8_1] = rKh1;
        *(uint4*)&sKl[srow0][sc8_0] = rKl0;
        *(uint4*)&sKl[srow1][sc8_1] = rKl1;
        *(uint4*)&sVT[srow0][sc8_0] = rVT0;
        *(uint4*)&sVT[srow1][sc8_1] = rVT1;
        // ---- bias / multiplier for this lane's 16 logits (current tile)
        ushort4 Bq[4]; float4 Uq[4];
#pragma unroll
        for (int sub = 0; sub < 4; ++sub) {
            Bq[sub] = *(const ushort4*)&Bm[brow + m0 + 16*sub + 4*g];
            Uq[sub] = *(const float4*)&mult[urow + m0 + 16*sub + 4*g];
        }
        __syncthreads();                     // LDS tile visible

        // ---- prefetch next tile into regs (overlaps with compute below)
        if (mt < 7) {
            int m1 = m0 + 64;
            rKh0 = *(const uint4*)&Kh[kbB + (long)(m1+srow0)*KD + sc8_0];
            rKh1 = *(const uint4*)&Kh[kbB + (long)(m1+srow1)*KD + sc8_1];
            rKl0 = *(const uint4*)&Kl[kbB + (long)(m1+srow0)*KD + sc8_0];
            rKl1 = *(const uint4*)&Kl[kbB + (long)(m1+srow1)*KD + sc8_1];
            rVT0 = *(const uint4*)&VhT[vtb + (long)srow0*N_SEQ + m1 + sc8_0];
            rVT1 = *(const uint4*)&VhT[vtb + (long)srow1*N_SEQ + m1 + sc8_1];
        }

        // ---- QK^T (swapped): S[sub] = K_sub * Q^T, split-bf16 3-term
        f32x4 S[4];
#pragma unroll
        for (int i = 0; i < 4; ++i) S[i] = {0.f, 0.f, 0.f, 0.f};
        __builtin_amdgcn_s_setprio(1);
#pragma unroll
        for (int ks = 0; ks < 2; ++ks) {
            v8s qh = ks ? qh1 : qh0;
            v8s ql = ks ? ql1 : ql0;
#pragma unroll
            for (int sub = 0; sub < 4; ++sub) {
                v8s kh = *(const v8s*)&sKh[16*sub + ln][32*ks + 8*g];
                v8s kl = *(const v8s*)&sKl[16*sub + ln][32*ks + 8*g];
                S[sub] = __builtin_amdgcn_mfma_f32_16x16x32_bf16(kh, qh, S[sub], 0, 0, 0);
                S[sub] = __builtin_amdgcn_mfma_f32_16x16x32_bf16(kl, qh, S[sub], 0, 0, 0);
                S[sub] = __builtin_amdgcn_mfma_f32_16x16x32_bf16(kh, ql, S[sub], 0, 0, 0);
            }
        }
        __builtin_amdgcn_s_setprio(0);

        // ---- logits + online softmax (lane-local row n = ln)
        float lg[16]; float mx = -1e30f;
#pragma unroll
        for (int sub = 0; sub < 4; ++sub) {
            float b0 = bf2f(Bq[sub].x), b1 = bf2f(Bq[sub].y);
            float b2 = bf2f(Bq[sub].z), b3 = bf2f(Bq[sub].w);
            lg[4*sub+0] = (S[sub][0] + b0) * Uq[sub].x * qs;
            lg[4*sub+1] = (S[sub][1] + b1) * Uq[sub].y * qs;
            lg[4*sub+2] = (S[sub][2] + b2) * Uq[sub].z * qs;
            lg[4*sub+3] = (S[sub][3] + b3) * Uq[sub].w * qs;
            mx = fmaxf(mx, fmaxf(fmaxf(lg[4*sub+0], lg[4*sub+1]),
                                 fmaxf(lg[4*sub+2], lg[4*sub+3])));
        }
        mx = fmaxf(mx, __shfl_xor(mx, 16));
        mx = fmaxf(mx, __shfl_xor(mx, 32));
        float Mn = fmaxf(M, mx);
        float sc = __expf(M - Mn);
        float ps = 0.f;
#pragma unroll
        for (int i = 0; i < 16; ++i) {
            float e = __expf(lg[i] - Mn);
            lg[i] = e; ps += e;
        }
        ps += __shfl_xor(ps, 16);
        ps += __shfl_xor(ps, 32);
        L = L * sc + ps; M = Mn;

        // ---- P -> bf16 in LDS (wave-private, no barrier needed)
#pragma unroll
        for (int sub = 0; sub < 4; ++sub)
            *(ushort4*)&sP[w][ln][16*sub + 4*g] =
                make_ushort4(f2bf(lg[4*sub+0]), f2bf(lg[4*sub+1]),
                             f2bf(lg[4*sub+2]), f2bf(lg[4*sub+3]));

        // ---- rescale O, then PV: O^T += V^T * P^T
#pragma unroll
        for (int i = 0; i < 4; ++i) accO[i] *= sc;
        __builtin_amdgcn_s_setprio(1);
#pragma unroll
        for (int ks = 0; ks < 2; ++ks) {
            v8s pp = *(const v8s*)&sP[w][ln][32*ks + 8*g];
#pragma unroll
            for (int sub = 0; sub < 4; ++sub) {
                v8s vh = *(const v8s*)&sVT[16*sub + ln][32*ks + 8*g];
                accO[sub] = __builtin_amdgcn_mfma_f32_16x16x32_bf16(vh, pp, accO[sub], 0, 0, 0);
            }
        }
        __builtin_amdgcn_s_setprio(0);
    }

    // ---- epilogue: unnormalized partial O^T (bf16) + (M, L)
    long ob = ((long)bid*64 + (w*16 + ln)) * 64;
#pragma unroll
    for (int sub = 0; sub < 4; ++sub)
        *(ushort4*)&Opart[ob + 16*sub + 4*g] =
            make_ushort4(f2bf(accO[sub][0]), f2bf(accO[sub][1]),
                         f2bf(accO[sub][2]), f2bf(accO[sub][3]));
    if (g == 0) {
        Mp[bid*64 + w*16 + ln] = M;
        Lp[bid*64 + w*16 + ln] = L;
    }
}

// ---------------------------------------------------------------------------
// Kernel 4: merge the four m-quarters (flash combine) + normalize.
// ---------------------------------------------------------------------------
__global__ __launch_bounds__(256) void combine_kernel(
    const ushort* __restrict__ Opart, const float* __restrict__ Mp,
    const float* __restrict__ Lp, float* __restrict__ out)
{
    int idx = blockIdx.x * 256 + threadIdx.x;   // 262144 float4-quads
    int kq = idx & 15;
    int row = idx >> 4;                          // b*2048 + n
    int b = row >> 11, n = row & 2047;
    int nt = n >> 6, r = n & 63;
    int bid0 = ((nt*4) << 3) | b;                // +8 per quarter
    float Mq[4], Lq[4];
#pragma unroll
    for (int p = 0; p < 4; ++p) {
        Mq[p] = Mp[(bid0 + 8*p)*64 + r];
        Lq[p] = Lp[(bid0 + 8*p)*64 + r];
    }
    float Mx = fmaxf(fmaxf(Mq[0], Mq[1]), fmaxf(Mq[2], Mq[3]));
    float4 acc = make_float4(0.f, 0.f, 0.f, 0.f);
    float Ls = 0.f;
#pragma unroll
    for (int p = 0; p < 4; ++p) {
        float e = __expf(Mq[p] - Mx);
        Ls += Lq[p] * e;
        ushort4 o = *(const ushort4*)&Opart[((long)(bid0 + 8*p)*64 + r)*64 + 4*kq];
        acc.x = fmaf(e, bf2f(o.x), acc.x);
        acc.y = fmaf(e, bf2f(o.y), acc.y);
        acc.z = fmaf(e, bf2f(o.z), acc.z);
        acc.w = fmaf(e, bf2f(o.w), acc.w);
    }
    float inv = 1.0f / Ls;
    float4 o;
    o.x = acc.x * inv; o.y = acc.y * inv;
    o.z = acc.z * inv; o.w = acc.w * inv;
    *(float4*)&out[(long)row*64 + 4*kq] = o;
}

// ---------------------------------------------------------------------------
extern "C" void kernel_launch(void* const* d_in, const int* in_sizes, int n_in,
                              void* d_out, int out_size, void* d_ws, size_t ws_size,
                              hipStream_t stream) {
    const float* src  = (const float*)d_in[0];
    const float* bias = (const float*)d_in[1];
    const float* mult = (const float*)d_in[2];
    const float* Wr   = (const float*)d_in[3];
    const float* Cc   = (const float*)d_in[4];
    const float* logp = (const float*)d_in[5];
    const float* Wq   = (const float*)d_in[6];
    const float* Wk   = (const float*)d_in[7];
    const float* Wv   = (const float*)d_in[8];
    const float* sp   = (const float*)d_in[9];
    float* outp = (float*)d_out;

    const size_t QKV_E = (size_t)NB * N_SEQ * KD;       // 1048576
    ushort* wsu = (ushort*)d_ws;
    ushort* Bm  = wsu;                                  // 8.39 MB
    ushort* Qh  = wsu + (size_t)N_SEQ * N_SEQ;          // 2.10 MB each
    ushort* Ql  = Qh + QKV_E;
    ushort* Kh  = Ql + QKV_E;
    ushort* Kl  = Kh + QKV_E;
    ushort* VhT = Kl + QKV_E;
    ushort* Opart = VhT + QKV_E;                        // 1024*64*64 bf16 = 8.39 MB
    float* Mp = (float*)(Opart + (size_t)1024 * 64 * 64);
    float* Lp = Mp + (size_t)1024 * 64;
    // Table overlays Opart (tbuild/ftheta complete before attn writes it).
    float2* Tp = (float2*)Opart;                        // 2 MB

    tbuild_kernel<<<(TG*TG)/256, 256, 0, stream>>>(Wr, Cc, Tp);
    ftheta_kernel<<<(N_SEQ*(long)N_SEQ)/512, 256, 0, stream>>>(bias, Tp, logp, Bm);
    qkv_kernel<<<(NB*N_SEQ)/32, 256, 0, stream>>>(src, Wq, Wk, Wv, Qh, Ql, Kh, Kl, VhT);
    attn_mfma_kernel<<<1024, 256, 0, stream>>>(Qh, Ql, Kh, Kl, VhT, Bm, mult, sp,
                                               Opart, Mp, Lp);
    combine_kernel<<<1024, 256, 0, stream>>>(Opart, Mp, Lp, outp);
}

// Round 7
// 131.396 us; speedup vs baseline: 2.6646x; 1.3745x over previous
//
#include <hip/hip_runtime.h>
#include <hip/hip_bf16.h>

#define N_SEQ 2048
#define NB 8
#define DM 512
#define KD 64
#define NF 70

#define TG 512                   // table grid
#define TRANGE 6.5f              // table covers [-TRANGE, TRANGE]
#define TSCL (511.0f / 13.0f)    // (TG-1) / (2*TRANGE)
#define TOFS (6.5f * TSCL)       // 255.5

typedef float f32x4 __attribute__((ext_vector_type(4)));
typedef short v8s  __attribute__((ext_vector_type(8)));

__device__ __forceinline__ ushort f2bf(float x) {
    uint u = __float_as_uint(x);
    return (ushort)((u + 0x7FFFu + ((u >> 16) & 1u)) >> 16);
}
__device__ __forceinline__ float bf2f(ushort h) {
    return __uint_as_float(((uint)h) << 16);
}

// ---------------------------------------------------------------------------
// Kernel 0a: scalar table  Tg[j][i] = g(x_i, y_j),
//   g(x,y) = sum_f C_f*sqrt2*sin(x*w0+y*w1+pi/4)
// ---------------------------------------------------------------------------
__global__ __launch_bounds__(256) void tbuild_kernel(
    const float* __restrict__ Wr, const float* __restrict__ Cc,
    float* __restrict__ Tg)
{
    const float SQ2 = 1.41421356237309504880f;
    const float R2PI = 0.15915494309189533577f;
    int idx = blockIdx.x * 256 + threadIdx.x;      // TG*TG threads
    int j = idx >> 9, i = idx & (TG - 1);
    const float h = 2.0f * TRANGE / (TG - 1);
    float y = -TRANGE + j * h;
    float x = -TRANGE + i * h;
    float g = 0.f;
    for (int f = 0; f < NF; ++f) {
        float w0 = Wr[2*f] * R2PI, w1 = Wr[2*f+1] * R2PI, cf = Cc[f];
        float k = __builtin_amdgcn_fractf(fmaf(x, w0, fmaf(y, w1, 0.125f)));
        g = fmaf(cf, __builtin_amdgcn_sinf(k), g);
    }
    Tg[idx] = g * SQ2;
}

// ---------------------------------------------------------------------------
// Kernel 0b: pack quads  T4[j][i] = (g[j][i], g[j][i+1], g[j+1][i], g[j+1][i+1])
// -> ONE dwordx4 load per bilinear lookup.
// ---------------------------------------------------------------------------
__global__ __launch_bounds__(256) void tpack_kernel(
    const float* __restrict__ Tg, float4* __restrict__ T4)
{
    int idx = blockIdx.x * 256 + threadIdx.x;
    int j = idx >> 9, i = idx & (TG - 1);
    int i1 = min(i + 1, TG - 1);
    int j1 = min(j + 1, TG - 1);
    float4 q;
    q.x = Tg[j*TG + i];
    q.y = Tg[j*TG + i1];
    q.z = Tg[j1*TG + i];
    q.w = Tg[j1*TG + i1];
    T4[idx] = q;
}

// ---------------------------------------------------------------------------
// Kernel 1: f_theta via single-load bilinear lookups -> Bmat bf16.
// ---------------------------------------------------------------------------
__device__ __forceinline__ float tlookup(const float4* __restrict__ T4,
                                         float x, float y)
{
    float u = fmaf(x, TSCL, TOFS);
    float v = fmaf(y, TSCL, TOFS);
    u = fminf(fmaxf(u, 0.0f), 510.999f);
    v = fminf(fmaxf(v, 0.0f), 510.999f);
    int iu = (int)u, iv = (int)v;
    float fu = __builtin_amdgcn_fractf(u);
    float fv = __builtin_amdgcn_fractf(v);
    float4 q = T4[iv * TG + iu];      // (v00, v10, v01, v11)
    float t0 = fmaf(fu, q.y - q.x, q.x);
    float t1 = fmaf(fu, q.w - q.z, q.z);
    return fmaf(fv, t1 - t0, t0);
}

__global__ __launch_bounds__(256) void ftheta_kernel(
    const float* __restrict__ bias, const float4* __restrict__ T4,
    const float* __restrict__ logp, ushort* __restrict__ Bm)
{
    int tid = threadIdx.x;
    long i0 = (long)blockIdx.x * 512 + tid;
    long i1 = i0 + 256;
    float4 a = ((const float4*)bias)[i0];
    float4 b = ((const float4*)bias)[i1];
    float gA1 = tlookup(T4, a.x, a.y);
    float gA2 = tlookup(T4, a.z, a.w);
    float gB1 = tlookup(T4, b.x, b.y);
    float gB2 = tlookup(T4, b.z, b.w);
    float s0 = fabsf(gA1 - gA2) + 1e-6f;
    float s1 = fabsf(gB1 - gB2) + 1e-6f;
    float p = __expf(logp[0]);
    p = fminf(fmaxf(p, 0.5f), 3.0f);
    if (p == 1.0f) {
        Bm[i0] = f2bf(__expf(-s0));
        Bm[i1] = f2bf(__expf(-s1));
    } else {
        Bm[i0] = f2bf(__expf(-__powf(s0, p)));
        Bm[i1] = f2bf(__expf(-__powf(s1, p)));
    }
}

// ---------------------------------------------------------------------------
// Kernel 2: QKV projection via MFMA (bf16 x bf16, fp32 acc).
// ---------------------------------------------------------------------------
__global__ __launch_bounds__(256) void qkv_kernel(
    const float* __restrict__ src, const float* __restrict__ Wq,
    const float* __restrict__ Wk, const float* __restrict__ Wv,
    ushort* __restrict__ Qh, ushort* __restrict__ Ql,
    ushort* __restrict__ Kh, ushort* __restrict__ Kl,
    ushort* __restrict__ VhT)
{
    __shared__ ushort sS[32][72];     // src rows (bf16), one 64-k chunk
    __shared__ ushort sW[192][72];    // Wq|Wk|Wv rows (bf16), one 64-k chunk
    int tid = threadIdx.x;
    int lane = tid & 63, w = tid >> 6;
    int wr = w >> 1, wc = w & 1;
    int g = lane >> 4, ln = lane & 15;
    int row0 = blockIdx.x * 32;

    f32x4 acc[6];
#pragma unroll
    for (int t = 0; t < 6; ++t) acc[t] = {0.f, 0.f, 0.f, 0.f};

    for (int kc = 0; kc < 8; ++kc) {
        int k0 = kc * 64;
        __syncthreads();
        {   // stage src chunk: 32x64, 1 slot (8 elems) per thread
            int r = tid >> 3, c8 = (tid & 7) * 8;
            float4 f0 = *(const float4*)&src[(long)(row0 + r)*DM + k0 + c8];
            float4 f1 = *(const float4*)&src[(long)(row0 + r)*DM + k0 + c8 + 4];
            *(ushort4*)&sS[r][c8] =
                make_ushort4(f2bf(f0.x), f2bf(f0.y), f2bf(f0.z), f2bf(f0.w));
            *(ushort4*)&sS[r][c8+4] =
                make_ushort4(f2bf(f1.x), f2bf(f1.y), f2bf(f1.z), f2bf(f1.w));
        }
        {   // stage W chunk: 192x64, 6 slots per thread
#pragma unroll
            for (int j = 0; j < 6; ++j) {
                int slot = tid + j*256;
                int r = slot >> 3, c8 = (slot & 7) * 8;
                const float* Wp = (r < 64) ? Wq : (r < 128 ? Wk : Wv);
                int rr = r & 63;
                float4 f0 = *(const float4*)&Wp[(long)rr*DM + k0 + c8];
                float4 f1 = *(const float4*)&Wp[(long)rr*DM + k0 + c8 + 4];
                *(ushort4*)&sW[r][c8] =
                    make_ushort4(f2bf(f0.x), f2bf(f0.y), f2bf(f0.z), f2bf(f0.w));
                *(ushort4*)&sW[r][c8+4] =
                    make_ushort4(f2bf(f1.x), f2bf(f1.y), f2bf(f1.z), f2bf(f1.w));
            }
        }
        __syncthreads();
#pragma unroll
        for (int kw = 0; kw < 2; ++kw) {
            v8s bsrc = *(const v8s*)&sS[16*wr + ln][32*kw + 8*g];
#pragma unroll
            for (int t = 0; t < 6; ++t) {
                v8s aw = *(const v8s*)&sW[96*wc + 16*t + ln][32*kw + 8*g];
                acc[t] = __builtin_amdgcn_mfma_f32_16x16x32_bf16(aw, bsrc, acc[t], 0, 0, 0);
            }
        }
    }
    int n = row0 + 16*wr + ln;
    int bb = n >> 11, nn = n & 2047;
#pragma unroll
    for (int t = 0; t < 6; ++t) {
#pragma unroll
        for (int i = 0; i < 4; ++i) {
            int c = 96*wc + 16*t + 4*g + i;
            float v = acc[t][i];
            if (c < 64) {
                ushort h = f2bf(v);
                Qh[(long)n*KD + c] = h;
                Ql[(long)n*KD + c] = f2bf(v - bf2f(h));
            } else if (c < 128) {
                int cc = c - 64;
                ushort h = f2bf(v);
                Kh[(long)n*KD + cc] = h;
                Kl[(long)n*KD + cc] = f2bf(v - bf2f(h));
            } else {
                int kv = c - 128;
                VhT[((long)bb*KD + kv)*N_SEQ + nn] = f2bf(v);
            }
        }
    }
}

// ---------------------------------------------------------------------------
// Kernel 3: MFMA flash attention. QBLK=128 (8 waves), m-split in 4 quarters.
// Per-wave: 16 q-rows, Q hi/lo in registers. K/V AND bias/mult are
// cross-iteration register prefetches (latency hidden under full iteration).
// bid = ((nt*4+p)<<3)|b  so batch == XCD (K/V L2-resident).
// ---------------------------------------------------------------------------
__global__ __launch_bounds__(512, 4) void attn_mfma_kernel(
    const ushort* __restrict__ Qh, const ushort* __restrict__ Ql,
    const ushort* __restrict__ Kh, const ushort* __restrict__ Kl,
    const ushort* __restrict__ VhT, const ushort* __restrict__ Bm,
    const float* __restrict__ mult, const float* __restrict__ sp,
    ushort* __restrict__ Opart, float* __restrict__ Mp, float* __restrict__ Lp)
{
    __shared__ ushort sKh[64][72], sKl[64][72];
    __shared__ ushort sVT[64][72];              // V^T: [kv][m]
    __shared__ ushort sP[8][16][72];            // per wave: [n][m]

    int tid = threadIdx.x;
    int lane = tid & 63, w = tid >> 6;          // w in 0..7
    int g = lane >> 4, ln = lane & 15;
    int bid = blockIdx.x;
    int b = bid & 7, rest = bid >> 3, p = rest & 3, nt = rest >> 2;
    int n0 = nt * 128;

    // ---- Q (hi/lo) into registers
    int qrow = n0 + w*16 + ln;
    long qoff = ((long)b*N_SEQ + qrow)*KD + 8*g;
    v8s qh0 = *(const v8s*)&Qh[qoff];
    v8s qh1 = *(const v8s*)&Qh[qoff + 32];
    v8s ql0 = *(const v8s*)&Ql[qoff];
    v8s ql1 = *(const v8s*)&Ql[qoff + 32];

    float s  = sp[0];
    float qs = 0.125f * s;
    float M = -1e30f, L = 0.f;
    f32x4 accO[4];
#pragma unroll
    for (int i = 0; i < 4; ++i) accO[i] = {0.f, 0.f, 0.f, 0.f};

    long brow = (long)qrow * N_SEQ;
    long urow = ((long)b*N_SEQ + qrow) * N_SEQ;
    long vtb  = (long)b*KD*N_SEQ;
    long kbB  = (long)b*N_SEQ*KD;

    // staging slot (one uint4 per buffer per thread; 512 thr cover 64x64 bf16)
    int srow = tid >> 3, sc8 = (tid & 7) * 8;

    // ---- prologue: prefetch tile 0 (K/V + bias/mult)
    uint4 rKh, rKl, rVT;
    ushort4 nBq[4]; float4 nUq[4];
    {
        int m0 = p*512;
        rKh = *(const uint4*)&Kh[kbB + (long)(m0+srow)*KD + sc8];
        rKl = *(const uint4*)&Kl[kbB + (long)(m0+srow)*KD + sc8];
        rVT = *(const uint4*)&VhT[vtb + (long)srow*N_SEQ + m0 + sc8];
#pragma unroll
        for (int sub = 0; sub < 4; ++sub) {
            nBq[sub] = *(const ushort4*)&Bm[brow + m0 + 16*sub + 4*g];
            nUq[sub] = *(const float4*)&mult[urow + m0 + 16*sub + 4*g];
        }
    }

    for (int mt = 0; mt < 8; ++mt) {
        int m0 = p*512 + mt*64;
        __syncthreads();                     // prev compute done reading LDS
        *(uint4*)&sKh[srow][sc8] = rKh;
        *(uint4*)&sKl[srow][sc8] = rKl;
        *(uint4*)&sVT[srow][sc8] = rVT;
        __syncthreads();                     // LDS tile visible

        // ---- prefetch next K/V tile into regs (overlaps with compute)
        if (mt < 7) {
            int m1 = m0 + 64;
            rKh = *(const uint4*)&Kh[kbB + (long)(m1+srow)*KD + sc8];
            rKl = *(const uint4*)&Kl[kbB + (long)(m1+srow)*KD + sc8];
            rVT = *(const uint4*)&VhT[vtb + (long)srow*N_SEQ + m1 + sc8];
        }

        // ---- QK^T (swapped): S[sub] = K_sub * Q^T, split-bf16 3-term
        f32x4 S[4];
#pragma unroll
        for (int i = 0; i < 4; ++i) S[i] = {0.f, 0.f, 0.f, 0.f};
        __builtin_amdgcn_s_setprio(1);
#pragma unroll
        for (int ks = 0; ks < 2; ++ks) {
            v8s qh = ks ? qh1 : qh0;
            v8s ql = ks ? ql1 : ql0;
#pragma unroll
            for (int sub = 0; sub < 4; ++sub) {
                v8s kh = *(const v8s*)&sKh[16*sub + ln][32*ks + 8*g];
                v8s kl = *(const v8s*)&sKl[16*sub + ln][32*ks + 8*g];
                S[sub] = __builtin_amdgcn_mfma_f32_16x16x32_bf16(kh, qh, S[sub], 0, 0, 0);
                S[sub] = __builtin_amdgcn_mfma_f32_16x16x32_bf16(kl, qh, S[sub], 0, 0, 0);
                S[sub] = __builtin_amdgcn_mfma_f32_16x16x32_bf16(kh, ql, S[sub], 0, 0, 0);
            }
        }
        __builtin_amdgcn_s_setprio(0);

        // ---- logits + online softmax (lane-local row n = ln), consume nB/nU
        float lg[16]; float mx = -1e30f;
#pragma unroll
        for (int sub = 0; sub < 4; ++sub) {
            float b0 = bf2f(nBq[sub].x), b1 = bf2f(nBq[sub].y);
            float b2 = bf2f(nBq[sub].z), b3 = bf2f(nBq[sub].w);
            lg[4*sub+0] = (S[sub][0] + b0) * nUq[sub].x * qs;
            lg[4*sub+1] = (S[sub][1] + b1) * nUq[sub].y * qs;
            lg[4*sub+2] = (S[sub][2] + b2) * nUq[sub].z * qs;
            lg[4*sub+3] = (S[sub][3] + b3) * nUq[sub].w * qs;
            mx = fmaxf(mx, fmaxf(fmaxf(lg[4*sub+0], lg[4*sub+1]),
                                 fmaxf(lg[4*sub+2], lg[4*sub+3])));
        }
        // ---- prefetch next bias/mult (full iteration of latency cover)
        if (mt < 7) {
            int m1 = m0 + 64;
#pragma unroll
            for (int sub = 0; sub < 4; ++sub) {
                nBq[sub] = *(const ushort4*)&Bm[brow + m1 + 16*sub + 4*g];
                nUq[sub] = *(const float4*)&mult[urow + m1 + 16*sub + 4*g];
            }
        }
        mx = fmaxf(mx, __shfl_xor(mx, 16));
        mx = fmaxf(mx, __shfl_xor(mx, 32));
        float Mn = fmaxf(M, mx);
        float sc = __expf(M - Mn);
        float ps = 0.f;
#pragma unroll
        for (int i = 0; i < 16; ++i) {
            float e = __expf(lg[i] - Mn);
            lg[i] = e; ps += e;
        }
        ps += __shfl_xor(ps, 16);
        ps += __shfl_xor(ps, 32);
        L = L * sc + ps; M = Mn;

        // ---- P -> bf16 in LDS (wave-private, no barrier needed)
#pragma unroll
        for (int sub = 0; sub < 4; ++sub)
            *(ushort4*)&sP[w][ln][16*sub + 4*g] =
                make_ushort4(f2bf(lg[4*sub+0]), f2bf(lg[4*sub+1]),
                             f2bf(lg[4*sub+2]), f2bf(lg[4*sub+3]));

        // ---- rescale O, then PV: O^T += V^T * P^T
#pragma unroll
        for (int i = 0; i < 4; ++i) accO[i] *= sc;
        __builtin_amdgcn_s_setprio(1);
#pragma unroll
        for (int ks = 0; ks < 2; ++ks) {
            v8s pp = *(const v8s*)&sP[w][ln][32*ks + 8*g];
#pragma unroll
            for (int sub = 0; sub < 4; ++sub) {
                v8s vh = *(const v8s*)&sVT[16*sub + ln][32*ks + 8*g];
                accO[sub] = __builtin_amdgcn_mfma_f32_16x16x32_bf16(vh, pp, accO[sub], 0, 0, 0);
            }
        }
        __builtin_amdgcn_s_setprio(0);
    }

    // ---- epilogue: unnormalized partial O^T (bf16) + (M, L)
    long ob = ((long)bid*128 + (w*16 + ln)) * 64;
#pragma unroll
    for (int sub = 0; sub < 4; ++sub)
        *(ushort4*)&Opart[ob + 16*sub + 4*g] =
            make_ushort4(f2bf(accO[sub][0]), f2bf(accO[sub][1]),
                         f2bf(accO[sub][2]), f2bf(accO[sub][3]));
    if (g == 0) {
        Mp[bid*128 + w*16 + ln] = M;
        Lp[bid*128 + w*16 + ln] = L;
    }
}

// ---------------------------------------------------------------------------
// Kernel 4: merge the four m-quarters (flash combine) + normalize.
// ---------------------------------------------------------------------------
__global__ __launch_bounds__(256) void combine_kernel(
    const ushort* __restrict__ Opart, const float* __restrict__ Mp,
    const float* __restrict__ Lp, float* __restrict__ out)
{
    int idx = blockIdx.x * 256 + threadIdx.x;   // 262144 float4-quads
    int kq = idx & 15;
    int row = idx >> 4;                          // b*2048 + n
    int b = row >> 11, n = row & 2047;
    int nt = n >> 7, r = n & 127;
    int bid0 = ((nt*4) << 3) | b;                // +8 per quarter
    float Mq[4], Lq[4];
#pragma unroll
    for (int p = 0; p < 4; ++p) {
        Mq[p] = Mp[(bid0 + 8*p)*128 + r];
        Lq[p] = Lp[(bid0 + 8*p)*128 + r];
    }
    float Mx = fmaxf(fmaxf(Mq[0], Mq[1]), fmaxf(Mq[2], Mq[3]));
    float4 acc = make_float4(0.f, 0.f, 0.f, 0.f);
    float Ls = 0.f;
#pragma unroll
    for (int p = 0; p < 4; ++p) {
        float e = __expf(Mq[p] - Mx);
        Ls += Lq[p] * e;
        ushort4 o = *(const ushort4*)&Opart[((long)(bid0 + 8*p)*128 + r)*64 + 4*kq];
        acc.x = fmaf(e, bf2f(o.x), acc.x);
        acc.y = fmaf(e, bf2f(o.y), acc.y);
        acc.z = fmaf(e, bf2f(o.z), acc.z);
        acc.w = fmaf(e, bf2f(o.w), acc.w);
    }
    float inv = 1.0f / Ls;
    float4 o;
    o.x = acc.x * inv; o.y = acc.y * inv;
    o.z = acc.z * inv; o.w = acc.w * inv;
    *(float4*)&out[(long)row*64 + 4*kq] = o;
}

// ---------------------------------------------------------------------------
extern "C" void kernel_launch(void* const* d_in, const int* in_sizes, int n_in,
                              void* d_out, int out_size, void* d_ws, size_t ws_size,
                              hipStream_t stream) {
    const float* src  = (const float*)d_in[0];
    const float* bias = (const float*)d_in[1];
    const float* mult = (const float*)d_in[2];
    const float* Wr   = (const float*)d_in[3];
    const float* Cc   = (const float*)d_in[4];
    const float* logp = (const float*)d_in[5];
    const float* Wq   = (const float*)d_in[6];
    const float* Wk   = (const float*)d_in[7];
    const float* Wv   = (const float*)d_in[8];
    const float* sp   = (const float*)d_in[9];
    float* outp = (float*)d_out;

    const size_t QKV_E = (size_t)NB * N_SEQ * KD;       // 1048576
    ushort* wsu = (ushort*)d_ws;
    ushort* Bm  = wsu;                                  // 8.39 MB
    ushort* Qh  = wsu + (size_t)N_SEQ * N_SEQ;
    ushort* Ql  = Qh + QKV_E;
    ushort* Kh  = Ql + QKV_E;
    ushort* Kl  = Kh + QKV_E;
    ushort* VhT = Kl + QKV_E;
    ushort* Opart = VhT + QKV_E;                        // 512*128*64 bf16 = 8.39 MB
    float* Mp = (float*)(Opart + (size_t)512 * 128 * 64);
    float* Lp = Mp + (size_t)512 * 128;
    float4* T4 = (float4*)(Lp + (size_t)512 * 128);     // 4 MB
    float*  Tg = (float*)(T4 + (size_t)TG * TG);        // 1 MB

    tbuild_kernel<<<(TG*TG)/256, 256, 0, stream>>>(Wr, Cc, Tg);
    tpack_kernel<<<(TG*TG)/256, 256, 0, stream>>>(Tg, T4);
    ftheta_kernel<<<(N_SEQ*(long)N_SEQ)/512, 256, 0, stream>>>(bias, T4, logp, Bm);
    qkv_kernel<<<(NB*N_SEQ)/32, 256, 0, stream>>>(src, Wq, Wk, Wv, Qh, Ql, Kh, Kl, VhT);
    attn_mfma_kernel<<<512, 512, 0, stream>>>(Qh, Ql, Kh, Kl, VhT, Bm, mult, sp,
                                              Opart, Mp, Lp);
    combine_kernel<<<1024, 256, 0, stream>>>(Opart, Mp, Lp, outp);
}

// Round 8
// 126.854 us; speedup vs baseline: 2.7600x; 1.0358x over previous
//
#include <hip/hip_runtime.h>
#include <hip/hip_bf16.h>

#define N_SEQ 2048
#define NB 8
#define DM 512
#define KD 64
#define NF 70

#define TG 512                   // table grid
#define TRANGE 6.5f              // table covers [-TRANGE, TRANGE]
#define TSCL (511.0f / 13.0f)    // (TG-1) / (2*TRANGE)
#define TOFS (6.5f * TSCL)       // 255.5

typedef float f32x4 __attribute__((ext_vector_type(4)));
typedef short v8s  __attribute__((ext_vector_type(8)));

__device__ __forceinline__ ushort f2bf(float x) {
    uint u = __float_as_uint(x);
    return (ushort)((u + 0x7FFFu + ((u >> 16) & 1u)) >> 16);
}
__device__ __forceinline__ float bf2f(ushort h) {
    return __uint_as_float(((uint)h) << 16);
}

// ---------------------------------------------------------------------------
// Kernel 0a: scalar table  Tg[j][i] = g(x_i, y_j),
//   g(x,y) = sum_f C_f*sqrt2*sin(x*w0+y*w1+pi/4)
// ---------------------------------------------------------------------------
__global__ __launch_bounds__(256) void tbuild_kernel(
    const float* __restrict__ Wr, const float* __restrict__ Cc,
    float* __restrict__ Tg)
{
    const float SQ2 = 1.41421356237309504880f;
    const float R2PI = 0.15915494309189533577f;
    int idx = blockIdx.x * 256 + threadIdx.x;      // TG*TG threads
    int j = idx >> 9, i = idx & (TG - 1);
    const float h = 2.0f * TRANGE / (TG - 1);
    float y = -TRANGE + j * h;
    float x = -TRANGE + i * h;
    float g = 0.f;
    for (int f = 0; f < NF; ++f) {
        float w0 = Wr[2*f] * R2PI, w1 = Wr[2*f+1] * R2PI, cf = Cc[f];
        float k = __builtin_amdgcn_fractf(fmaf(x, w0, fmaf(y, w1, 0.125f)));
        g = fmaf(cf, __builtin_amdgcn_sinf(k), g);
    }
    Tg[idx] = g * SQ2;
}

// ---------------------------------------------------------------------------
// Kernel 0b: pack quads  T4[j][i] = (g[j][i], g[j][i+1], g[j+1][i], g[j+1][i+1])
// -> ONE dwordx4 load per bilinear lookup.
// ---------------------------------------------------------------------------
__global__ __launch_bounds__(256) void tpack_kernel(
    const float* __restrict__ Tg, float4* __restrict__ T4)
{
    int idx = blockIdx.x * 256 + threadIdx.x;
    int j = idx >> 9, i = idx & (TG - 1);
    int i1 = min(i + 1, TG - 1);
    int j1 = min(j + 1, TG - 1);
    float4 q;
    q.x = Tg[j*TG + i];
    q.y = Tg[j*TG + i1];
    q.z = Tg[j1*TG + i];
    q.w = Tg[j1*TG + i1];
    T4[idx] = q;
}

// ---------------------------------------------------------------------------
// Kernel 1: f_theta via single-load bilinear lookups -> Bmat bf16.
// ---------------------------------------------------------------------------
__device__ __forceinline__ float tlookup(const float4* __restrict__ T4,
                                         float x, float y)
{
    float u = fmaf(x, TSCL, TOFS);
    float v = fmaf(y, TSCL, TOFS);
    u = fminf(fmaxf(u, 0.0f), 510.999f);
    v = fminf(fmaxf(v, 0.0f), 510.999f);
    int iu = (int)u, iv = (int)v;
    float fu = __builtin_amdgcn_fractf(u);
    float fv = __builtin_amdgcn_fractf(v);
    float4 q = T4[iv * TG + iu];      // (v00, v10, v01, v11)
    float t0 = fmaf(fu, q.y - q.x, q.x);
    float t1 = fmaf(fu, q.w - q.z, q.z);
    return fmaf(fv, t1 - t0, t0);
}

__global__ __launch_bounds__(256) void ftheta_kernel(
    const float* __restrict__ bias, const float4* __restrict__ T4,
    const float* __restrict__ logp, ushort* __restrict__ Bm)
{
    int tid = threadIdx.x;
    long i0 = (long)blockIdx.x * 512 + tid;
    long i1 = i0 + 256;
    float4 a = ((const float4*)bias)[i0];
    float4 b = ((const float4*)bias)[i1];
    float gA1 = tlookup(T4, a.x, a.y);
    float gA2 = tlookup(T4, a.z, a.w);
    float gB1 = tlookup(T4, b.x, b.y);
    float gB2 = tlookup(T4, b.z, b.w);
    float s0 = fabsf(gA1 - gA2) + 1e-6f;
    float s1 = fabsf(gB1 - gB2) + 1e-6f;
    float p = __expf(logp[0]);
    p = fminf(fmaxf(p, 0.5f), 3.0f);
    if (p == 1.0f) {
        Bm[i0] = f2bf(__expf(-s0));
        Bm[i1] = f2bf(__expf(-s1));
    } else {
        Bm[i0] = f2bf(__expf(-__powf(s0, p)));
        Bm[i1] = f2bf(__expf(-__powf(s1, p)));
    }
}

// ---------------------------------------------------------------------------
// Kernel 2: QKV projection via MFMA (bf16 x bf16, fp32 acc).
// Emits hi/lo-split bf16 Q, hi-only bf16 K, transposed bf16 V.
// ---------------------------------------------------------------------------
__global__ __launch_bounds__(256) void qkv_kernel(
    const float* __restrict__ src, const float* __restrict__ Wq,
    const float* __restrict__ Wk, const float* __restrict__ Wv,
    ushort* __restrict__ Qh, ushort* __restrict__ Ql,
    ushort* __restrict__ Kh, ushort* __restrict__ VhT)
{
    __shared__ ushort sS[32][72];     // src rows (bf16), one 64-k chunk
    __shared__ ushort sW[192][72];    // Wq|Wk|Wv rows (bf16), one 64-k chunk
    int tid = threadIdx.x;
    int lane = tid & 63, w = tid >> 6;
    int wr = w >> 1, wc = w & 1;
    int g = lane >> 4, ln = lane & 15;
    int row0 = blockIdx.x * 32;

    f32x4 acc[6];
#pragma unroll
    for (int t = 0; t < 6; ++t) acc[t] = {0.f, 0.f, 0.f, 0.f};

    for (int kc = 0; kc < 8; ++kc) {
        int k0 = kc * 64;
        __syncthreads();
        {   // stage src chunk: 32x64, 1 slot (8 elems) per thread
            int r = tid >> 3, c8 = (tid & 7) * 8;
            float4 f0 = *(const float4*)&src[(long)(row0 + r)*DM + k0 + c8];
            float4 f1 = *(const float4*)&src[(long)(row0 + r)*DM + k0 + c8 + 4];
            *(ushort4*)&sS[r][c8] =
                make_ushort4(f2bf(f0.x), f2bf(f0.y), f2bf(f0.z), f2bf(f0.w));
            *(ushort4*)&sS[r][c8+4] =
                make_ushort4(f2bf(f1.x), f2bf(f1.y), f2bf(f1.z), f2bf(f1.w));
        }
        {   // stage W chunk: 192x64, 6 slots per thread
#pragma unroll
            for (int j = 0; j < 6; ++j) {
                int slot = tid + j*256;
                int r = slot >> 3, c8 = (slot & 7) * 8;
                const float* Wp = (r < 64) ? Wq : (r < 128 ? Wk : Wv);
                int rr = r & 63;
                float4 f0 = *(const float4*)&Wp[(long)rr*DM + k0 + c8];
                float4 f1 = *(const float4*)&Wp[(long)rr*DM + k0 + c8 + 4];
                *(ushort4*)&sW[r][c8] =
                    make_ushort4(f2bf(f0.x), f2bf(f0.y), f2bf(f0.z), f2bf(f0.w));
                *(ushort4*)&sW[r][c8+4] =
                    make_ushort4(f2bf(f1.x), f2bf(f1.y), f2bf(f1.z), f2bf(f1.w));
            }
        }
        __syncthreads();
#pragma unroll
        for (int kw = 0; kw < 2; ++kw) {
            v8s bsrc = *(const v8s*)&sS[16*wr + ln][32*kw + 8*g];
#pragma unroll
            for (int t = 0; t < 6; ++t) {
                v8s aw = *(const v8s*)&sW[96*wc + 16*t + ln][32*kw + 8*g];
                acc[t] = __builtin_amdgcn_mfma_f32_16x16x32_bf16(aw, bsrc, acc[t], 0, 0, 0);
            }
        }
    }
    int n = row0 + 16*wr + ln;
    int bb = n >> 11, nn = n & 2047;
#pragma unroll
    for (int t = 0; t < 6; ++t) {
        int c0 = 96*wc + 16*t + 4*g;
        f32x4 v = acc[t];
        ushort4 h = make_ushort4(f2bf(v[0]), f2bf(v[1]), f2bf(v[2]), f2bf(v[3]));
        if (c0 < 64) {
            *(ushort4*)&Qh[(long)n*KD + c0] = h;
            *(ushort4*)&Ql[(long)n*KD + c0] =
                make_ushort4(f2bf(v[0] - bf2f(h.x)), f2bf(v[1] - bf2f(h.y)),
                             f2bf(v[2] - bf2f(h.z)), f2bf(v[3] - bf2f(h.w)));
        } else if (c0 < 128) {
            *(ushort4*)&Kh[(long)n*KD + (c0 - 64)] = h;
        } else {
            int kv = c0 - 128;
            VhT[((long)bb*KD + kv + 0)*N_SEQ + nn] = h.x;
            VhT[((long)bb*KD + kv + 1)*N_SEQ + nn] = h.y;
            VhT[((long)bb*KD + kv + 2)*N_SEQ + nn] = h.z;
            VhT[((long)bb*KD + kv + 3)*N_SEQ + nn] = h.w;
        }
    }
}

// ---------------------------------------------------------------------------
// Kernel 3: MFMA flash attention. QBLK=64 (4 waves), m-split in 4 quarters.
// 2-term split QK: S = Kh*(Qh+Ql) (K_lo term ~2e-3 on logits, dropped).
// Grid 1024 = 4 blocks/CU fully resident (LDS 27.6KB, VGPR<=128).
// K/V and bias/mult are cross-iteration register prefetches.
// bid = ((nt*4+p)<<3)|b  so batch == XCD (K/V L2-resident).
// ---------------------------------------------------------------------------
__global__ __launch_bounds__(256, 4) void attn_mfma_kernel(
    const ushort* __restrict__ Qh, const ushort* __restrict__ Ql,
    const ushort* __restrict__ Kh, const ushort* __restrict__ VhT,
    const ushort* __restrict__ Bm, const float* __restrict__ mult,
    const float* __restrict__ sp,
    ushort* __restrict__ Opart, float* __restrict__ Mp, float* __restrict__ Lp)
{
    __shared__ ushort sKh[64][72];
    __shared__ ushort sVT[64][72];              // V^T: [kv][m]
    __shared__ ushort sP[4][16][72];            // per wave: [n][m]

    int tid = threadIdx.x;
    int lane = tid & 63, w = tid >> 6;          // w in 0..3
    int g = lane >> 4, ln = lane & 15;
    int bid = blockIdx.x;
    int b = bid & 7, rest = bid >> 3, p = rest & 3, nt = rest >> 2;
    int n0 = nt * 64;

    // ---- Q (hi/lo) into registers
    int qrow = n0 + w*16 + ln;
    long qoff = ((long)b*N_SEQ + qrow)*KD + 8*g;
    v8s qh0 = *(const v8s*)&Qh[qoff];
    v8s qh1 = *(const v8s*)&Qh[qoff + 32];
    v8s ql0 = *(const v8s*)&Ql[qoff];
    v8s ql1 = *(const v8s*)&Ql[qoff + 32];

    float s  = sp[0];
    float qs = 0.125f * s;
    float M = -1e30f, L = 0.f;
    f32x4 accO[4];
#pragma unroll
    for (int i = 0; i < 4; ++i) accO[i] = {0.f, 0.f, 0.f, 0.f};

    long brow = (long)qrow * N_SEQ;
    long urow = ((long)b*N_SEQ + qrow) * N_SEQ;
    long vtb  = (long)b*KD*N_SEQ;
    long kbB  = (long)b*N_SEQ*KD;

    // staging slots (two uint4 per buffer per thread; 256 thr cover 64x64 bf16)
    int srow = tid >> 3, sc8 = (tid & 7) * 8;   // srow 0..31, +32 second half

    // ---- prologue: prefetch tile 0 (K/V + bias/mult)
    uint4 rKh0, rKh1, rVT0, rVT1;
    ushort4 nBq[4]; float4 nUq[4];
    {
        int m0 = p*512;
        rKh0 = *(const uint4*)&Kh[kbB + (long)(m0+srow)*KD + sc8];
        rKh1 = *(const uint4*)&Kh[kbB + (long)(m0+srow+32)*KD + sc8];
        rVT0 = *(const uint4*)&VhT[vtb + (long)srow*N_SEQ + m0 + sc8];
        rVT1 = *(const uint4*)&VhT[vtb + (long)(srow+32)*N_SEQ + m0 + sc8];
#pragma unroll
        for (int sub = 0; sub < 4; ++sub) {
            nBq[sub] = *(const ushort4*)&Bm[brow + m0 + 16*sub + 4*g];
            nUq[sub] = *(const float4*)&mult[urow + m0 + 16*sub + 4*g];
        }
    }

    for (int mt = 0; mt < 8; ++mt) {
        int m0 = p*512 + mt*64;
        __syncthreads();                     // prev compute done reading LDS
        *(uint4*)&sKh[srow][sc8]      = rKh0;
        *(uint4*)&sKh[srow + 32][sc8] = rKh1;
        *(uint4*)&sVT[srow][sc8]      = rVT0;
        *(uint4*)&sVT[srow + 32][sc8] = rVT1;
        __syncthreads();                     // LDS tile visible

        // ---- prefetch next K/V tile into regs (overlaps with compute)
        if (mt < 7) {
            int m1 = m0 + 64;
            rKh0 = *(const uint4*)&Kh[kbB + (long)(m1+srow)*KD + sc8];
            rKh1 = *(const uint4*)&Kh[kbB + (long)(m1+srow+32)*KD + sc8];
            rVT0 = *(const uint4*)&VhT[vtb + (long)srow*N_SEQ + m1 + sc8];
            rVT1 = *(const uint4*)&VhT[vtb + (long)(srow+32)*N_SEQ + m1 + sc8];
        }

        // ---- QK^T (swapped): S[sub] = Kh_sub * (Qh+Ql)^T, 2-term split
        f32x4 S[4];
#pragma unroll
        for (int i = 0; i < 4; ++i) S[i] = {0.f, 0.f, 0.f, 0.f};
        __builtin_amdgcn_s_setprio(1);
#pragma unroll
        for (int ks = 0; ks < 2; ++ks) {
            v8s qh = ks ? qh1 : qh0;
            v8s ql = ks ? ql1 : ql0;
#pragma unroll
            for (int sub = 0; sub < 4; ++sub) {
                v8s kh = *(const v8s*)&sKh[16*sub + ln][32*ks + 8*g];
                S[sub] = __builtin_amdgcn_mfma_f32_16x16x32_bf16(kh, qh, S[sub], 0, 0, 0);
                S[sub] = __builtin_amdgcn_mfma_f32_16x16x32_bf16(kh, ql, S[sub], 0, 0, 0);
            }
        }
        __builtin_amdgcn_s_setprio(0);

        // ---- logits + online softmax (lane-local row n = ln), consume nB/nU
        float lg[16]; float mx = -1e30f;
#pragma unroll
        for (int sub = 0; sub < 4; ++sub) {
            float b0 = bf2f(nBq[sub].x), b1 = bf2f(nBq[sub].y);
            float b2 = bf2f(nBq[sub].z), b3 = bf2f(nBq[sub].w);
            lg[4*sub+0] = (S[sub][0] + b0) * nUq[sub].x * qs;
            lg[4*sub+1] = (S[sub][1] + b1) * nUq[sub].y * qs;
            lg[4*sub+2] = (S[sub][2] + b2) * nUq[sub].z * qs;
            lg[4*sub+3] = (S[sub][3] + b3) * nUq[sub].w * qs;
            mx = fmaxf(mx, fmaxf(fmaxf(lg[4*sub+0], lg[4*sub+1]),
                                 fmaxf(lg[4*sub+2], lg[4*sub+3])));
        }
        // ---- prefetch next bias/mult (full iteration of latency cover)
        if (mt < 7) {
            int m1 = m0 + 64;
#pragma unroll
            for (int sub = 0; sub < 4; ++sub) {
                nBq[sub] = *(const ushort4*)&Bm[brow + m1 + 16*sub + 4*g];
                nUq[sub] = *(const float4*)&mult[urow + m1 + 16*sub + 4*g];
            }
        }
        mx = fmaxf(mx, __shfl_xor(mx, 16));
        mx = fmaxf(mx, __shfl_xor(mx, 32));
        float Mn = fmaxf(M, mx);
        float sc = __expf(M - Mn);
        float ps = 0.f;
#pragma unroll
        for (int i = 0; i < 16; ++i) {
            float e = __expf(lg[i] - Mn);
            lg[i] = e; ps += e;
        }
        ps += __shfl_xor(ps, 16);
        ps += __shfl_xor(ps, 32);
        L = L * sc + ps; M = Mn;

        // ---- P -> bf16 in LDS (wave-private, no barrier needed)
#pragma unroll
        for (int sub = 0; sub < 4; ++sub)
            *(ushort4*)&sP[w][ln][16*sub + 4*g] =
                make_ushort4(f2bf(lg[4*sub+0]), f2bf(lg[4*sub+1]),
                             f2bf(lg[4*sub+2]), f2bf(lg[4*sub+3]));

        // ---- rescale O, then PV: O^T += V^T * P^T
#pragma unroll
        for (int i = 0; i < 4; ++i) accO[i] *= sc;
        __builtin_amdgcn_s_setprio(1);
#pragma unroll
        for (int ks = 0; ks < 2; ++ks) {
            v8s pp = *(const v8s*)&sP[w][ln][32*ks + 8*g];
#pragma unroll
            for (int sub = 0; sub < 4; ++sub) {
                v8s vh = *(const v8s*)&sVT[16*sub + ln][32*ks + 8*g];
                accO[sub] = __builtin_amdgcn_mfma_f32_16x16x32_bf16(vh, pp, accO[sub], 0, 0, 0);
            }
        }
        __builtin_amdgcn_s_setprio(0);
    }

    // ---- epilogue: unnormalized partial O^T (bf16) + (M, L)
    long ob = ((long)bid*64 + (w*16 + ln)) * 64;
#pragma unroll
    for (int sub = 0; sub < 4; ++sub)
        *(ushort4*)&Opart[ob + 16*sub + 4*g] =
            make_ushort4(f2bf(accO[sub][0]), f2bf(accO[sub][1]),
                         f2bf(accO[sub][2]), f2bf(accO[sub][3]));
    if (g == 0) {
        Mp[bid*64 + w*16 + ln] = M;
        Lp[bid*64 + w*16 + ln] = L;
    }
}

// ---------------------------------------------------------------------------
// Kernel 4: merge the four m-quarters (flash combine) + normalize.
// ---------------------------------------------------------------------------
__global__ __launch_bounds__(256) void combine_kernel(
    const ushort* __restrict__ Opart, const float* __restrict__ Mp,
    const float* __restrict__ Lp, float* __restrict__ out)
{
    int idx = blockIdx.x * 256 + threadIdx.x;   // 262144 float4-quads
    int kq = idx & 15;
    int row = idx >> 4;                          // b*2048 + n
    int b = row >> 11, n = row & 2047;
    int nt = n >> 6, r = n & 63;
    int bid0 = ((nt*4) << 3) | b;                // +8 per quarter
    float Mq[4], Lq[4];
#pragma unroll
    for (int p = 0; p < 4; ++p) {
        Mq[p] = Mp[(bid0 + 8*p)*64 + r];
        Lq[p] = Lp[(bid0 + 8*p)*64 + r];
    }
    float Mx = fmaxf(fmaxf(Mq[0], Mq[1]), fmaxf(Mq[2], Mq[3]));
    float4 acc = make_float4(0.f, 0.f, 0.f, 0.f);
    float Ls = 0.f;
#pragma unroll
    for (int p = 0; p < 4; ++p) {
        float e = __expf(Mq[p] - Mx);
        Ls += Lq[p] * e;
        ushort4 o = *(const ushort4*)&Opart[((long)(bid0 + 8*p)*64 + r)*64 + 4*kq];
        acc.x = fmaf(e, bf2f(o.x), acc.x);
        acc.y = fmaf(e, bf2f(o.y), acc.y);
        acc.z = fmaf(e, bf2f(o.z), acc.z);
        acc.w = fmaf(e, bf2f(o.w), acc.w);
    }
    float inv = 1.0f / Ls;
    float4 o;
    o.x = acc.x * inv; o.y = acc.y * inv;
    o.z = acc.z * inv; o.w = acc.w * inv;
    *(float4*)&out[(long)row*64 + 4*kq] = o;
}

// ---------------------------------------------------------------------------
extern "C" void kernel_launch(void* const* d_in, const int* in_sizes, int n_in,
                              void* d_out, int out_size, void* d_ws, size_t ws_size,
                              hipStream_t stream) {
    const float* src  = (const float*)d_in[0];
    const float* bias = (const float*)d_in[1];
    const float* mult = (const float*)d_in[2];
    const float* Wr   = (const float*)d_in[3];
    const float* Cc   = (const float*)d_in[4];
    const float* logp = (const float*)d_in[5];
    const float* Wq   = (const float*)d_in[6];
    const float* Wk   = (const float*)d_in[7];
    const float* Wv   = (const float*)d_in[8];
    const float* sp   = (const float*)d_in[9];
    float* outp = (float*)d_out;

    const size_t QKV_E = (size_t)NB * N_SEQ * KD;       // 1048576
    ushort* wsu = (ushort*)d_ws;
    ushort* Bm  = wsu;                                  // 8.39 MB
    ushort* Qh  = wsu + (size_t)N_SEQ * N_SEQ;
    ushort* Ql  = Qh + QKV_E;
    ushort* Kh  = Ql + QKV_E;
    ushort* VhT = Kh + QKV_E;
    ushort* Opart = VhT + QKV_E;                        // 1024*64*64 bf16 = 8.39 MB
    float* Mp = (float*)(Opart + (size_t)1024 * 64 * 64);
    float* Lp = Mp + (size_t)1024 * 64;
    float4* T4 = (float4*)(Lp + (size_t)1024 * 64);     // 4 MB
    float*  Tg = (float*)(T4 + (size_t)TG * TG);        // 1 MB

    tbuild_kernel<<<(TG*TG)/256, 256, 0, stream>>>(Wr, Cc, Tg);
    tpack_kernel<<<(TG*TG)/256, 256, 0, stream>>>(Tg, T4);
    ftheta_kernel<<<(N_SEQ*(long)N_SEQ)/512, 256, 0, stream>>>(bias, T4, logp, Bm);
    qkv_kernel<<<(NB*N_SEQ)/32, 256, 0, stream>>>(src, Wq, Wk, Wv, Qh, Ql, Kh, VhT);
    attn_mfma_kernel<<<1024, 256, 0, stream>>>(Qh, Ql, Kh, VhT, Bm, mult, sp,
                                               Opart, Mp, Lp);
    combine_kernel<<<1024, 256, 0, stream>>>(Opart, Mp, Lp, outp);
}